// Round 2
// baseline (2547.627 us; speedup 1.0000x reference)
//
#include <hip/hip_runtime.h>

// JTNN encoder, MI355X.
//  - hU = h @ Ur_w computed once per row, gathered (5x FLOP cut vs h_nei@Ur)
//  - x-side projections folded into per-VOCAB tables (780 rows, L2-resident)
//  - depth-0 closed form: h1 = sigma(embZ[v]) * tanh(embH[v])  (table lookup)
//  - message phase chunked (C=4) to fit 244 MiB workspace
//  - GRU update fused into P-GEMM epilogue; sigmoid fused into Z-GEMM epilogue

#define HD 256
#define NNODES 65536
#define NMESS 131072
#define NVOCAB 780
#define NTREES 2048
#define MAXNEI 5
#define NCHUNK 4
#define MC (NMESS / NCHUNK)   // 32768 rows per chunk

typedef short bfrag __attribute__((ext_vector_type(8)));   // 8 bf16 in 4 VGPRs
typedef float f32x4v __attribute__((ext_vector_type(4)));

__device__ __forceinline__ float bf2f(unsigned short u) {
    union { unsigned int u; float f; } v; v.u = ((unsigned int)u) << 16; return v.f;
}
__device__ __forceinline__ unsigned short f2bf(float f) {
    union { float f; unsigned int u; } v; v.f = f;
    unsigned int r = v.u + 0x7FFFu + ((v.u >> 16) & 1u);
    return (unsigned short)(r >> 16);
}
__device__ __forceinline__ float sigm(float x) { return 1.f / (1.f + __expf(-x)); }
__device__ __forceinline__ float tanh_fast(float x) {
    float e = __expf(2.f * x); return 1.f - 2.f / (e + 1.f);
}

// ---------------- precompute: per-vocab projection tables -------------------
__global__ __launch_bounds__(256) void prep_tables(
    const float* __restrict__ emb,
    const float* __restrict__ Wz_w, const float* __restrict__ Wz_b,
    const float* __restrict__ Wr_w, const float* __restrict__ Ur_b,
    const float* __restrict__ Wh_w, const float* __restrict__ Wh_b,
    const float* __restrict__ out_w, const float* __restrict__ out_b,
    float* __restrict__ embR, float* __restrict__ embZ,
    float* __restrict__ embH, float* __restrict__ embO,
    unsigned short* __restrict__ h1tab)
{
    __shared__ __align__(16) float e[4][HD];
    int t = threadIdx.x;
    int b0 = blockIdx.x * 4;
    for (int r = 0; r < 4; r++) e[r][t] = emb[(b0 + r) * HD + t];
    __syncthreads();
    float br = Ur_b[t], bz = Wz_b[t], bh = Wh_b[t], bo = out_b[t];
    float aR[4], aZ[4], aH[4], aO[4];
    for (int r = 0; r < 4; r++) { aR[r] = br; aZ[r] = bz; aH[r] = bh; aO[r] = bo; }
    for (int k = 0; k < HD; k++) {
        float wr = Wr_w[k * HD + t];
        float wz = Wz_w[k * HD + t];
        float wh = Wh_w[k * HD + t];
        float wo = out_w[k * HD + t];
        #pragma unroll
        for (int r = 0; r < 4; r++) {
            float ev = e[r][k];
            aR[r] += ev * wr; aZ[r] += ev * wz; aH[r] += ev * wh; aO[r] += ev * wo;
        }
    }
    for (int r = 0; r < 4; r++) {
        embR[(b0 + r) * HD + t] = aR[r];
        embZ[(b0 + r) * HD + t] = aZ[r];
        embH[(b0 + r) * HD + t] = aH[r];
        embO[(b0 + r) * HD + t] = aO[r];
        // depth-0 closed form: h1 = sigmoid(embZ)*tanh(embH)
        h1tab[(b0 + r) * HD + t] = f2bf(sigm(aZ[r]) * tanh_fast(aH[r]));
    }
}

// transpose weight blocks to bf16 [N][K] (B^T layout for MFMA)
__global__ __launch_bounds__(256) void prep_wt(
    const float* __restrict__ Ur_w, const float* __restrict__ Wz_w,
    const float* __restrict__ Wh_w, const float* __restrict__ out_w,
    unsigned short* __restrict__ UrT, unsigned short* __restrict__ Wz2T,
    unsigned short* __restrict__ Wh2T, unsigned short* __restrict__ Wo2T)
{
    int idx = blockIdx.x * 256 + threadIdx.x;   // n*256 + k
    int n = idx >> 8, k = idx & 255;
    UrT[idx]  = f2bf(Ur_w[k * HD + n]);
    Wz2T[idx] = f2bf(Wz_w[(HD + k) * HD + n]);
    Wh2T[idx] = f2bf(Wh_w[(HD + k) * HD + n]);
    Wo2T[idx] = f2bf(out_w[(HD + k) * HD + n]);
}

__global__ __launch_bounds__(256) void prep_vmess(
    const int* __restrict__ fnode, const int* __restrict__ fmess,
    int* __restrict__ v_mess)
{
    int m = blockIdx.x * 256 + threadIdx.x;
    v_mess[m] = fnode[fmess[m]];
}

// depth-0 fill: h[m] = h1tab[v_mess[m]], h[0] = 0
__global__ __launch_bounds__(256) void fill_h1(
    const unsigned short* __restrict__ h1tab, const int* __restrict__ v_mess,
    unsigned short* __restrict__ h)
{
    int t = blockIdx.x * 256 + threadIdx.x;
    int m = t >> 6;
    int c = (t & 63) * 4;
    ushort4 o = *(const ushort4*)&h1tab[v_mess[m] * HD + c];
    if (m == 0) { o.x = o.y = o.z = o.w = 0; }
    *(ushort4*)&h[(size_t)m * HD + c] = o;
}

// ---------------- MFMA GEMM: C[rows,256] = A[rows,256] @ B, Bt as [256,256] --
// MODE 0: store bf16 (hU)
// MODE 1: Z epilogue: store sigmoid(acc + embZ[vid]) bf16
// MODE 2: P epilogue: pre=tanh(acc+embH[vid]); z=zbuf; h_next=((1-z)*sum_h+z*pre)*mask
// MODE 3: out epilogue: store relu(acc + embO[vid]) f32
#define BM 128
#define BN 128
#define BK 64
#define LDA (BK + 8)    // +8 bf16 pad (16B) -> conflict-free-ish LDS banking

template<int MODE>
__global__ __launch_bounds__(256) void gemm_tile(
    const unsigned short* __restrict__ A, const unsigned short* __restrict__ Bt,
    void* __restrict__ C,
    const float* __restrict__ etab, const int* __restrict__ vids,
    const unsigned short* __restrict__ zbuf, const unsigned short* __restrict__ shbuf,
    int row_base)
{
    __shared__ __align__(16) unsigned short As[BM * LDA];
    __shared__ __align__(16) unsigned short Bs[BN * LDA];
    int tid = threadIdx.x;
    int wave = tid >> 6, lane = tid & 63;
    int wm = wave >> 1, wn = wave & 1;          // 2x2 wave grid, 64x64 each
    int quad = lane >> 4, l16 = lane & 15;
    int col0 = blockIdx.x * BN;
    int row0 = blockIdx.y * BM;

    f32x4v acc[4][4] = {};

    for (int k0 = 0; k0 < HD; k0 += BK) {
        #pragma unroll
        for (int i = 0; i < 4; i++) {
            int idx = tid + i * 256;            // 0..1023
            int r = idx >> 3;
            int ck = (idx & 7) << 3;
            uint4 va = *(const uint4*)&A[(size_t)(row0 + r) * HD + k0 + ck];
            *(uint4*)&As[r * LDA + ck] = va;
            uint4 vb = *(const uint4*)&Bt[(size_t)(col0 + r) * HD + k0 + ck];
            *(uint4*)&Bs[r * LDA + ck] = vb;
        }
        __syncthreads();
        #pragma unroll
        for (int ks = 0; ks < BK; ks += 32) {
            bfrag af[4], bff[4];
            #pragma unroll
            for (int i = 0; i < 4; i++)
                af[i] = *(const bfrag*)&As[(wm * 64 + i * 16 + l16) * LDA + ks + quad * 8];
            #pragma unroll
            for (int j = 0; j < 4; j++)
                bff[j] = *(const bfrag*)&Bs[(wn * 64 + j * 16 + l16) * LDA + ks + quad * 8];
            #pragma unroll
            for (int i = 0; i < 4; i++)
                #pragma unroll
                for (int j = 0; j < 4; j++)
                    acc[i][j] = __builtin_amdgcn_mfma_f32_16x16x32_bf16(af[i], bff[j], acc[i][j], 0, 0, 0);
        }
        __syncthreads();
    }
    // epilogue: D elem (row = quad*4+r, col = l16) per 16x16 tile
    #pragma unroll
    for (int i = 0; i < 4; i++) {
        #pragma unroll
        for (int j = 0; j < 4; j++) {
            int Cc = col0 + wn * 64 + j * 16 + l16;
            #pragma unroll
            for (int r = 0; r < 4; r++) {
                int Rr = row0 + wm * 64 + i * 16 + quad * 4 + r;
                float v = acc[i][j][r];
                if (MODE == 0) {
                    ((unsigned short*)C)[(size_t)Rr * HD + Cc] = f2bf(v);
                } else if (MODE == 1) {
                    float z = sigm(v + etab[vids[Rr] * HD + Cc]);
                    ((unsigned short*)C)[(size_t)Rr * HD + Cc] = f2bf(z);
                } else if (MODE == 2) {
                    float pre = tanh_fast(v + etab[vids[Rr] * HD + Cc]);
                    float z = bf2f(zbuf[(size_t)Rr * HD + Cc]);
                    float sh = bf2f(shbuf[(size_t)Rr * HD + Cc]);
                    float hn = (1.f - z) * sh + z * pre;
                    if (row_base + Rr == 0) hn = 0.f;
                    ((unsigned short*)C)[(size_t)Rr * HD + Cc] = f2bf(hn);
                } else {
                    float o = v + etab[vids[Rr] * HD + Cc];
                    ((float*)C)[(size_t)Rr * HD + Cc] = fmaxf(o, 0.f);
                }
            }
        }
    }
}

// ---------------- gather + r-gate (one chunk): sum_h, sum_gh ----------------
__global__ __launch_bounds__(256) void gather_gru(
    const unsigned short* __restrict__ h, const unsigned short* __restrict__ hU,
    const int* __restrict__ mg, const int* __restrict__ v_mess,
    const float* __restrict__ embR,
    unsigned short* __restrict__ sum_h, unsigned short* __restrict__ sum_gh)
{
    int wave = threadIdx.x >> 6, lane = threadIdx.x & 63;
    int m = blockIdx.x * 4 + wave;              // chunk-local row
    int c = lane * 4;
    int v = v_mess[m];                          // v_mess pre-offset by chunk
    float4 rb = *(const float4*)&embR[v * HD + c];
    float ah0 = 0, ah1 = 0, ah2 = 0, ah3 = 0;
    float ag0 = 0, ag1 = 0, ag2 = 0, ag3 = 0;
    #pragma unroll
    for (int k = 0; k < MAXNEI; k++) {
        int j = mg[m * MAXNEI + k];             // mg pre-offset; j is GLOBAL row
        ushort4 hv = *(const ushort4*)&h[(size_t)j * HD + c];
        ushort4 uv = *(const ushort4*)&hU[(size_t)j * HD + c];
        float h0 = bf2f(hv.x), h1 = bf2f(hv.y), h2 = bf2f(hv.z), h3 = bf2f(hv.w);
        ah0 += h0; ah1 += h1; ah2 += h2; ah3 += h3;
        ag0 += sigm(rb.x + bf2f(uv.x)) * h0;
        ag1 += sigm(rb.y + bf2f(uv.y)) * h1;
        ag2 += sigm(rb.z + bf2f(uv.z)) * h2;
        ag3 += sigm(rb.w + bf2f(uv.w)) * h3;
    }
    ushort4 o;
    o.x = f2bf(ah0); o.y = f2bf(ah1); o.z = f2bf(ah2); o.w = f2bf(ah3);
    *(ushort4*)&sum_h[(size_t)m * HD + c] = o;
    o.x = f2bf(ag0); o.y = f2bf(ag1); o.z = f2bf(ag2); o.w = f2bf(ag3);
    *(ushort4*)&sum_gh[(size_t)m * HD + c] = o;
}

// ---------------- node-side neighbor sum ------------------------------------
__global__ __launch_bounds__(256) void gather_nodes(
    const unsigned short* __restrict__ h, const int* __restrict__ ng,
    unsigned short* __restrict__ mess_nei)
{
    int wave = threadIdx.x >> 6, lane = threadIdx.x & 63;
    int n = blockIdx.x * 4 + wave;
    int c = lane * 4;
    float a0 = 0, a1 = 0, a2 = 0, a3 = 0;
    #pragma unroll
    for (int k = 0; k < MAXNEI; k++) {
        int j = ng[n * MAXNEI + k];
        ushort4 hv = *(const ushort4*)&h[(size_t)j * HD + c];
        a0 += bf2f(hv.x); a1 += bf2f(hv.y); a2 += bf2f(hv.z); a3 += bf2f(hv.w);
    }
    ushort4 o;
    o.x = f2bf(a0); o.y = f2bf(a1); o.z = f2bf(a2); o.w = f2bf(a3);
    *(ushort4*)&mess_nei[(size_t)n * HD + c] = o;
}

// ---------------- per-tree segment mean (scope_ids sorted) ------------------
__device__ __forceinline__ int lower_bound_dev(const int* a, int n, int key) {
    int lo = 0, hi = n;
    while (lo < hi) { int mid = (lo + hi) >> 1; if (a[mid] < key) lo = mid + 1; else hi = mid; }
    return lo;
}

__global__ __launch_bounds__(256) void segment_mean(
    const float* __restrict__ node_vec, const int* __restrict__ scope,
    float* __restrict__ out)
{
    int t = blockIdx.x;
    int c = threadIdx.x;
    int lo = lower_bound_dev(scope, NNODES, t);
    int hi = lower_bound_dev(scope, NNODES, t + 1);
    float acc = 0.f;
    for (int n = lo; n < hi; n++) acc += node_vec[(size_t)n * HD + c];
    int cnt = hi - lo;
    out[t * HD + c] = cnt > 0 ? acc / (float)cnt : 0.f;
}

// ---------------------------------------------------------------------------
extern "C" void kernel_launch(void* const* d_in, const int* in_sizes, int n_in,
                              void* d_out, int out_size, void* d_ws, size_t ws_size,
                              hipStream_t stream)
{
    const int*   fnode      = (const int*)d_in[0];
    const int*   fmess      = (const int*)d_in[1];
    const int*   node_graph = (const int*)d_in[2];
    const int*   mess_graph = (const int*)d_in[3];
    const int*   scope_ids  = (const int*)d_in[4];
    const float* emb        = (const float*)d_in[5];
    const float* Wz_w       = (const float*)d_in[6];
    const float* Wz_b       = (const float*)d_in[7];
    const float* Wr_w       = (const float*)d_in[8];
    const float* Ur_w       = (const float*)d_in[9];
    const float* Ur_b       = (const float*)d_in[10];
    const float* Wh_w       = (const float*)d_in[11];
    const float* Wh_b       = (const float*)d_in[12];
    const float* out_w      = (const float*)d_in[13];
    const float* out_b      = (const float*)d_in[14];

    // ---- workspace carve (total 256,301,056 B = 244.4 MiB) ----
    char* ws = (char*)d_ws;
    const size_t MHB = (size_t)NMESS * HD * 2;         // 64 MiB bf16 full-M
    const size_t CHB = (size_t)MC * HD * 2;            // 16 MiB bf16 chunk
    unsigned short* P0 = (unsigned short*)ws; ws += MHB;
    unsigned short* P1 = (unsigned short*)ws; ws += MHB;
    unsigned short* PU = (unsigned short*)ws; ws += MHB;
    unsigned short* sum_h_c  = (unsigned short*)ws; ws += CHB;
    unsigned short* sum_gh_c = (unsigned short*)ws; ws += CHB;
    unsigned short* z_c      = (unsigned short*)ws; ws += CHB;
    float* embR = (float*)ws; ws += (size_t)NVOCAB * HD * 4;
    float* embZ = (float*)ws; ws += (size_t)NVOCAB * HD * 4;
    float* embH = (float*)ws; ws += (size_t)NVOCAB * HD * 4;
    float* embO = (float*)ws; ws += (size_t)NVOCAB * HD * 4;
    unsigned short* h1tab = (unsigned short*)ws; ws += (size_t)NVOCAB * HD * 2;
    unsigned short* UrT   = (unsigned short*)ws; ws += (size_t)HD * HD * 2;
    unsigned short* Wz2T  = (unsigned short*)ws; ws += (size_t)HD * HD * 2;
    unsigned short* Wh2T  = (unsigned short*)ws; ws += (size_t)HD * HD * 2;
    unsigned short* Wo2T  = (unsigned short*)ws; ws += (size_t)HD * HD * 2;
    int* v_mess = (int*)ws; ws += (size_t)NMESS * 4;
    if ((size_t)(ws - (char*)d_ws) > ws_size) return;  // ws too small: fail loud, not fault

    prep_tables<<<NVOCAB / 4, 256, 0, stream>>>(emb, Wz_w, Wz_b, Wr_w, Ur_b,
                                                Wh_w, Wh_b, out_w, out_b,
                                                embR, embZ, embH, embO, h1tab);
    prep_wt<<<HD * HD / 256, 256, 0, stream>>>(Ur_w, Wz_w, Wh_w, out_w,
                                               UrT, Wz2T, Wh2T, Wo2T);
    prep_vmess<<<NMESS / 256, 256, 0, stream>>>(fnode, fmess, v_mess);
    fill_h1<<<NMESS * 64 / 256, 256, 0, stream>>>(h1tab, v_mess, P0);

    unsigned short* hc = P0;
    unsigned short* hn = P1;
    dim3 gfull(HD / BN, NMESS / BM);
    dim3 gchunk(HD / BN, MC / BM);
    for (int d = 1; d < 6; d++) {
        gemm_tile<0><<<gfull, 256, 0, stream>>>(hc, UrT, PU, nullptr, nullptr,
                                                nullptr, nullptr, 0);
        for (int c = 0; c < NCHUNK; c++) {
            int rb = c * MC;
            gather_gru<<<MC / 4, 256, 0, stream>>>(hc, PU, mess_graph + (size_t)rb * MAXNEI,
                                                   v_mess + rb, embR, sum_h_c, sum_gh_c);
            gemm_tile<1><<<gchunk, 256, 0, stream>>>(sum_h_c, Wz2T, z_c, embZ,
                                                     v_mess + rb, nullptr, nullptr, 0);
            gemm_tile<2><<<gchunk, 256, 0, stream>>>(sum_gh_c, Wh2T, hn + (size_t)rb * HD,
                                                     embH, v_mess + rb, z_c, sum_h_c, rb);
        }
        unsigned short* tmp = hc; hc = hn; hn = tmp;
    }
    // final h is in hc (= P1 after 5 swaps); P0 and PU are free
    unsigned short* mess_nei = PU;
    float* node_vec = (float*)P0;              // 64 MiB exact fit
    gather_nodes<<<NNODES / 4, 256, 0, stream>>>(hc, node_graph, mess_nei);
    dim3 gout(HD / BN, NNODES / BM);
    gemm_tile<3><<<gout, 256, 0, stream>>>(mess_nei, Wo2T, node_vec, embO, fnode,
                                           nullptr, nullptr, 0);
    segment_mean<<<NTREES, 256, 0, stream>>>(node_vec, scope_ids, (float*)d_out);
}

// Round 3
// 1756.371 us; speedup vs baseline: 1.4505x; 1.4505x over previous
//
#include <hip/hip_runtime.h>

// JTNN encoder, MI355X.
//  - hU = h @ Ur_w computed once per row, gathered (5x FLOP cut vs h_nei@Ur)
//  - x-side projections folded into per-VOCAB tables (780 rows, L2-resident)
//  - depth-0 closed form: h1 = sigma(embZ[v]) * tanh(embH[v])  (table lookup)
//  - GEMM: global_load_lds width-16 DMA staging + XOR-swizzled LDS (no pad,
//    <=2-way bank aliasing = free), BN=256 full-width so A is read once
//  - gather: 2 messages/wave, 16B/lane loads (5 loads/message)

#define HD 256
#define NNODES 65536
#define NMESS 131072
#define NVOCAB 780
#define NTREES 2048
#define MAXNEI 5
#define NCHUNK 4
#define MC (NMESS / NCHUNK)   // 32768 rows per chunk
#define BM 128

typedef short bfrag __attribute__((ext_vector_type(8)));   // 8 bf16 in 4 VGPRs
typedef short s16x8 __attribute__((ext_vector_type(8)));
typedef float f32x4v __attribute__((ext_vector_type(4)));

__device__ __forceinline__ float bf2f(unsigned short u) {
    union { unsigned int u; float f; } v; v.u = ((unsigned int)u) << 16; return v.f;
}
__device__ __forceinline__ unsigned short f2bf(float f) {
    union { float f; unsigned int u; } v; v.f = f;
    unsigned int r = v.u + 0x7FFFu + ((v.u >> 16) & 1u);
    return (unsigned short)(r >> 16);
}
__device__ __forceinline__ float sigm(float x) { return 1.f / (1.f + __expf(-x)); }
__device__ __forceinline__ float tanh_fast(float x) {
    float e = __expf(2.f * x); return 1.f - 2.f / (e + 1.f);
}
// async global->LDS DMA, 16B per lane; lds dest must be wave-uniform base
__device__ __forceinline__ void async16(const unsigned short* g, unsigned short* l) {
    __builtin_amdgcn_global_load_lds(
        (const __attribute__((address_space(1))) unsigned int*)(g),
        (__attribute__((address_space(3))) unsigned int*)(l), 16, 0, 0);
}

// ---------------- precompute: per-vocab projection tables -------------------
__global__ __launch_bounds__(256) void prep_tables(
    const float* __restrict__ emb,
    const float* __restrict__ Wz_w, const float* __restrict__ Wz_b,
    const float* __restrict__ Wr_w, const float* __restrict__ Ur_b,
    const float* __restrict__ Wh_w, const float* __restrict__ Wh_b,
    const float* __restrict__ out_w, const float* __restrict__ out_b,
    float* __restrict__ embR, float* __restrict__ embZ,
    float* __restrict__ embH, float* __restrict__ embO,
    unsigned short* __restrict__ h1tab)
{
    __shared__ __align__(16) float e[4][HD];
    int t = threadIdx.x;
    int b0 = blockIdx.x * 4;
    for (int r = 0; r < 4; r++) e[r][t] = emb[(b0 + r) * HD + t];
    __syncthreads();
    float br = Ur_b[t], bz = Wz_b[t], bh = Wh_b[t], bo = out_b[t];
    float aR[4], aZ[4], aH[4], aO[4];
    for (int r = 0; r < 4; r++) { aR[r] = br; aZ[r] = bz; aH[r] = bh; aO[r] = bo; }
    for (int k = 0; k < HD; k++) {
        float wr = Wr_w[k * HD + t];
        float wz = Wz_w[k * HD + t];
        float wh = Wh_w[k * HD + t];
        float wo = out_w[k * HD + t];
        #pragma unroll
        for (int r = 0; r < 4; r++) {
            float ev = e[r][k];
            aR[r] += ev * wr; aZ[r] += ev * wz; aH[r] += ev * wh; aO[r] += ev * wo;
        }
    }
    for (int r = 0; r < 4; r++) {
        embR[(b0 + r) * HD + t] = aR[r];
        embZ[(b0 + r) * HD + t] = aZ[r];
        embH[(b0 + r) * HD + t] = aH[r];
        embO[(b0 + r) * HD + t] = aO[r];
        h1tab[(b0 + r) * HD + t] = f2bf(sigm(aZ[r]) * tanh_fast(aH[r]));
    }
}

// transpose weight blocks to bf16 [N][K] (B^T layout for MFMA)
__global__ __launch_bounds__(256) void prep_wt(
    const float* __restrict__ Ur_w, const float* __restrict__ Wz_w,
    const float* __restrict__ Wh_w, const float* __restrict__ out_w,
    unsigned short* __restrict__ UrT, unsigned short* __restrict__ Wz2T,
    unsigned short* __restrict__ Wh2T, unsigned short* __restrict__ Wo2T)
{
    int idx = blockIdx.x * 256 + threadIdx.x;   // n*256 + k
    int n = idx >> 8, k = idx & 255;
    UrT[idx]  = f2bf(Ur_w[k * HD + n]);
    Wz2T[idx] = f2bf(Wz_w[(HD + k) * HD + n]);
    Wh2T[idx] = f2bf(Wh_w[(HD + k) * HD + n]);
    Wo2T[idx] = f2bf(out_w[(HD + k) * HD + n]);
}

__global__ __launch_bounds__(256) void prep_vmess(
    const int* __restrict__ fnode, const int* __restrict__ fmess,
    int* __restrict__ v_mess)
{
    int m = blockIdx.x * 256 + threadIdx.x;
    v_mess[m] = fnode[fmess[m]];
}

// depth-0 fill: h[m] = h1tab[v_mess[m]], h[0] = 0   (16B/lane)
__global__ __launch_bounds__(256) void fill_h1(
    const unsigned short* __restrict__ h1tab, const int* __restrict__ v_mess,
    unsigned short* __restrict__ h)
{
    int t = blockIdx.x * 256 + threadIdx.x;
    int m = t >> 5;
    int c = (t & 31) * 8;
    s16x8 o = *(const s16x8*)&h1tab[v_mess[m] * HD + c];
    if (m == 0) o = (s16x8){0, 0, 0, 0, 0, 0, 0, 0};
    *(s16x8*)&h[(size_t)m * HD + c] = o;
}

// ---------------- MFMA GEMM: C[rows,256] = A[rows,256] @ B, Bt as [256,256] --
// BM=128, BN=256 (full width), BK=64, 512 threads (2x4 wave grid, 64x64/wave).
// LDS: XOR-swizzled chunk layout — row r's global 16B-chunk q lives at position
// p = q ^ (r&7).  Staged by global_load_lds (lane-contiguous dest), fragments
// read with ds_read_b128 at <=2-way bank aliasing (free).
// MODE 0: store bf16 (hU)
// MODE 1: Z epilogue: store sigmoid(acc + embZ[vid]) bf16
// MODE 2: P epilogue: pre=tanh(acc+embH[vid]); h_next=((1-z)*sum_h+z*pre)*mask
// MODE 3: out epilogue: store relu(acc + embO[vid]) f32
template<int MODE>
__global__ __launch_bounds__(512) void gemm_tile(
    const unsigned short* __restrict__ A, const unsigned short* __restrict__ Bt,
    void* __restrict__ C,
    const float* __restrict__ etab, const int* __restrict__ vids,
    const unsigned short* __restrict__ zbuf, const unsigned short* __restrict__ shbuf,
    int row_base)
{
    __shared__ __align__(16) unsigned short As[BM * 64];    // 16 KiB
    __shared__ __align__(16) unsigned short Bs[HD * 64];    // 32 KiB
    int tid = threadIdx.x;
    int wave = tid >> 6, lane = tid & 63;
    int wm = wave >> 2, wn = wave & 3;          // 2x4 wave grid, 64x64 each
    int quad = lane >> 4, l16 = lane & 15;
    int row0 = blockIdx.x * BM;

    // staging address precompute: A chunks c = wave*2+{0,1}; B chunks c = wave*4+{0..3}
    const unsigned short* aG[2]; unsigned short* aL[2];
    const unsigned short* bG[4]; unsigned short* bL[4];
    #pragma unroll
    for (int u = 0; u < 2; u++) {
        int cch = wave * 2 + u;
        int s = cch * 64 + lane;
        int r = s >> 3, p = s & 7, q = p ^ (r & 7);
        aG[u] = A + (size_t)(row0 + r) * HD + q * 8;
        aL[u] = &As[cch * 512];                 // wave-uniform
    }
    #pragma unroll
    for (int u = 0; u < 4; u++) {
        int cch = wave * 4 + u;
        int s = cch * 64 + lane;
        int r = s >> 3, p = s & 7, q = p ^ (r & 7);
        bG[u] = Bt + (size_t)r * HD + q * 8;
        bL[u] = &Bs[cch * 512];
    }

    f32x4v acc[4][4] = {};

    for (int k0 = 0; k0 < HD; k0 += 64) {
        #pragma unroll
        for (int u = 0; u < 2; u++) async16(aG[u] + k0, aL[u]);
        #pragma unroll
        for (int u = 0; u < 4; u++) async16(bG[u] + k0, bL[u]);
        __syncthreads();                        // drains vmcnt before barrier
        #pragma unroll
        for (int ks = 0; ks < 64; ks += 32) {
            bfrag af[4], bff[4];
            #pragma unroll
            for (int i = 0; i < 4; i++) {
                int r = wm * 64 + i * 16 + l16;
                int q = (ks >> 3) + quad, p = q ^ (r & 7);
                af[i] = *(const bfrag*)&As[r * 64 + p * 8];
            }
            #pragma unroll
            for (int j = 0; j < 4; j++) {
                int r = wn * 64 + j * 16 + l16;
                int q = (ks >> 3) + quad, p = q ^ (r & 7);
                bff[j] = *(const bfrag*)&Bs[r * 64 + p * 8];
            }
            #pragma unroll
            for (int i = 0; i < 4; i++)
                #pragma unroll
                for (int j = 0; j < 4; j++)
                    acc[i][j] = __builtin_amdgcn_mfma_f32_16x16x32_bf16(af[i], bff[j], acc[i][j], 0, 0, 0);
        }
        __syncthreads();
    }
    // epilogue: D elem (row = quad*4+r, col = l16) per 16x16 tile
    #pragma unroll
    for (int i = 0; i < 4; i++) {
        #pragma unroll
        for (int j = 0; j < 4; j++) {
            int Cc = wn * 64 + j * 16 + l16;
            #pragma unroll
            for (int r = 0; r < 4; r++) {
                int Rr = row0 + wm * 64 + i * 16 + quad * 4 + r;
                float v = acc[i][j][r];
                if (MODE == 0) {
                    ((unsigned short*)C)[(size_t)Rr * HD + Cc] = f2bf(v);
                } else if (MODE == 1) {
                    float z = sigm(v + etab[vids[Rr] * HD + Cc]);
                    ((unsigned short*)C)[(size_t)Rr * HD + Cc] = f2bf(z);
                } else if (MODE == 2) {
                    float pre = tanh_fast(v + etab[vids[Rr] * HD + Cc]);
                    float z = bf2f(zbuf[(size_t)Rr * HD + Cc]);
                    float sh = bf2f(shbuf[(size_t)Rr * HD + Cc]);
                    float hn = (1.f - z) * sh + z * pre;
                    if (row_base + Rr == 0) hn = 0.f;
                    ((unsigned short*)C)[(size_t)Rr * HD + Cc] = f2bf(hn);
                } else {
                    float o = v + etab[vids[Rr] * HD + Cc];
                    ((float*)C)[(size_t)Rr * HD + Cc] = fmaxf(o, 0.f);
                }
            }
        }
    }
}

// ---------------- gather + r-gate (one chunk): sum_h, sum_gh ----------------
// 2 messages per wave (half-wave each), 16B/lane loads: 5 loads/message/array
__global__ __launch_bounds__(256) void gather_gru(
    const unsigned short* __restrict__ h, const unsigned short* __restrict__ hU,
    const int* __restrict__ mg, const int* __restrict__ v_mess,
    const float* __restrict__ embR,
    unsigned short* __restrict__ sum_h, unsigned short* __restrict__ sum_gh)
{
    int wave = threadIdx.x >> 6, lane = threadIdx.x & 63;
    int half = lane >> 5, li = lane & 31;
    int m = blockIdx.x * 8 + wave * 2 + half;   // chunk-local row
    int c = li * 8;
    int v = v_mess[m];                          // v_mess pre-offset by chunk
    float rb[8];
    *(float4*)&rb[0] = *(const float4*)&embR[v * HD + c];
    *(float4*)&rb[4] = *(const float4*)&embR[v * HD + c + 4];
    float ah[8] = {0, 0, 0, 0, 0, 0, 0, 0};
    float ag[8] = {0, 0, 0, 0, 0, 0, 0, 0};
    #pragma unroll
    for (int k = 0; k < MAXNEI; k++) {
        int j = mg[m * MAXNEI + k];             // mg pre-offset; j is GLOBAL row
        s16x8 hv = *(const s16x8*)&h[(size_t)j * HD + c];
        s16x8 uv = *(const s16x8*)&hU[(size_t)j * HD + c];
        #pragma unroll
        for (int e = 0; e < 8; e++) {
            float hf = bf2f((unsigned short)hv[e]);
            ah[e] += hf;
            ag[e] += sigm(rb[e] + bf2f((unsigned short)uv[e])) * hf;
        }
    }
    s16x8 oh, og;
    #pragma unroll
    for (int e = 0; e < 8; e++) { oh[e] = (short)f2bf(ah[e]); og[e] = (short)f2bf(ag[e]); }
    *(s16x8*)&sum_h[(size_t)m * HD + c] = oh;
    *(s16x8*)&sum_gh[(size_t)m * HD + c] = og;
}

// ---------------- node-side neighbor sum (2 nodes/wave, 16B loads) ----------
__global__ __launch_bounds__(256) void gather_nodes(
    const unsigned short* __restrict__ h, const int* __restrict__ ng,
    unsigned short* __restrict__ mess_nei)
{
    int wave = threadIdx.x >> 6, lane = threadIdx.x & 63;
    int half = lane >> 5, li = lane & 31;
    int n = blockIdx.x * 8 + wave * 2 + half;
    int c = li * 8;
    float a[8] = {0, 0, 0, 0, 0, 0, 0, 0};
    #pragma unroll
    for (int k = 0; k < MAXNEI; k++) {
        int j = ng[n * MAXNEI + k];
        s16x8 hv = *(const s16x8*)&h[(size_t)j * HD + c];
        #pragma unroll
        for (int e = 0; e < 8; e++) a[e] += bf2f((unsigned short)hv[e]);
    }
    s16x8 o;
    #pragma unroll
    for (int e = 0; e < 8; e++) o[e] = (short)f2bf(a[e]);
    *(s16x8*)&mess_nei[(size_t)n * HD + c] = o;
}

// ---------------- per-tree segment mean (scope_ids sorted) ------------------
__device__ __forceinline__ int lower_bound_dev(const int* a, int n, int key) {
    int lo = 0, hi = n;
    while (lo < hi) { int mid = (lo + hi) >> 1; if (a[mid] < key) lo = mid + 1; else hi = mid; }
    return lo;
}

__global__ __launch_bounds__(256) void segment_mean(
    const float* __restrict__ node_vec, const int* __restrict__ scope,
    float* __restrict__ out)
{
    int t = blockIdx.x;
    int c = threadIdx.x;
    int lo = lower_bound_dev(scope, NNODES, t);
    int hi = lower_bound_dev(scope, NNODES, t + 1);
    float acc = 0.f;
    for (int n = lo; n < hi; n++) acc += node_vec[(size_t)n * HD + c];
    int cnt = hi - lo;
    out[t * HD + c] = cnt > 0 ? acc / (float)cnt : 0.f;
}

// ---------------------------------------------------------------------------
extern "C" void kernel_launch(void* const* d_in, const int* in_sizes, int n_in,
                              void* d_out, int out_size, void* d_ws, size_t ws_size,
                              hipStream_t stream)
{
    const int*   fnode      = (const int*)d_in[0];
    const int*   fmess      = (const int*)d_in[1];
    const int*   node_graph = (const int*)d_in[2];
    const int*   mess_graph = (const int*)d_in[3];
    const int*   scope_ids  = (const int*)d_in[4];
    const float* emb        = (const float*)d_in[5];
    const float* Wz_w       = (const float*)d_in[6];
    const float* Wz_b       = (const float*)d_in[7];
    const float* Wr_w       = (const float*)d_in[8];
    const float* Ur_w       = (const float*)d_in[9];
    const float* Ur_b       = (const float*)d_in[10];
    const float* Wh_w       = (const float*)d_in[11];
    const float* Wh_b       = (const float*)d_in[12];
    const float* out_w      = (const float*)d_in[13];
    const float* out_b      = (const float*)d_in[14];

    // ---- workspace carve (244.4 MiB) ----
    char* ws = (char*)d_ws;
    const size_t MHB = (size_t)NMESS * HD * 2;         // 64 MiB bf16 full-M
    const size_t CHB = (size_t)MC * HD * 2;            // 16 MiB bf16 chunk
    unsigned short* P0 = (unsigned short*)ws; ws += MHB;
    unsigned short* P1 = (unsigned short*)ws; ws += MHB;
    unsigned short* PU = (unsigned short*)ws; ws += MHB;
    unsigned short* sum_h_c  = (unsigned short*)ws; ws += CHB;
    unsigned short* sum_gh_c = (unsigned short*)ws; ws += CHB;
    unsigned short* z_c      = (unsigned short*)ws; ws += CHB;
    float* embR = (float*)ws; ws += (size_t)NVOCAB * HD * 4;
    float* embZ = (float*)ws; ws += (size_t)NVOCAB * HD * 4;
    float* embH = (float*)ws; ws += (size_t)NVOCAB * HD * 4;
    float* embO = (float*)ws; ws += (size_t)NVOCAB * HD * 4;
    unsigned short* h1tab = (unsigned short*)ws; ws += (size_t)NVOCAB * HD * 2;
    unsigned short* UrT   = (unsigned short*)ws; ws += (size_t)HD * HD * 2;
    unsigned short* Wz2T  = (unsigned short*)ws; ws += (size_t)HD * HD * 2;
    unsigned short* Wh2T  = (unsigned short*)ws; ws += (size_t)HD * HD * 2;
    unsigned short* Wo2T  = (unsigned short*)ws; ws += (size_t)HD * HD * 2;
    int* v_mess = (int*)ws; ws += (size_t)NMESS * 4;
    if ((size_t)(ws - (char*)d_ws) > ws_size) return;  // fail loud, not fault

    prep_tables<<<NVOCAB / 4, 256, 0, stream>>>(emb, Wz_w, Wz_b, Wr_w, Ur_b,
                                                Wh_w, Wh_b, out_w, out_b,
                                                embR, embZ, embH, embO, h1tab);
    prep_wt<<<HD * HD / 256, 256, 0, stream>>>(Ur_w, Wz_w, Wh_w, out_w,
                                               UrT, Wz2T, Wh2T, Wo2T);
    prep_vmess<<<NMESS / 256, 256, 0, stream>>>(fnode, fmess, v_mess);
    fill_h1<<<NMESS * 32 / 256, 256, 0, stream>>>(h1tab, v_mess, P0);

    unsigned short* hc = P0;
    unsigned short* hn = P1;
    for (int d = 1; d < 6; d++) {
        gemm_tile<0><<<NMESS / BM, 512, 0, stream>>>(hc, UrT, PU, nullptr, nullptr,
                                                     nullptr, nullptr, 0);
        for (int c = 0; c < NCHUNK; c++) {
            int rb = c * MC;
            gather_gru<<<MC / 8, 256, 0, stream>>>(hc, PU, mess_graph + (size_t)rb * MAXNEI,
                                                   v_mess + rb, embR, sum_h_c, sum_gh_c);
            gemm_tile<1><<<MC / BM, 512, 0, stream>>>(sum_h_c, Wz2T, z_c, embZ,
                                                      v_mess + rb, nullptr, nullptr, 0);
            gemm_tile<2><<<MC / BM, 512, 0, stream>>>(sum_gh_c, Wh2T, hn + (size_t)rb * HD,
                                                      embH, v_mess + rb, z_c, sum_h_c, rb);
        }
        unsigned short* tmp = hc; hc = hn; hn = tmp;
    }
    // final h is in hc; P0-or-P1 (hn) and PU are free
    unsigned short* mess_nei = PU;
    float* node_vec = (float*)hn;              // 64 MiB exact fit
    gather_nodes<<<NNODES / 8, 256, 0, stream>>>(hc, node_graph, mess_nei);
    gemm_tile<3><<<NNODES / BM, 512, 0, stream>>>(mess_nei, Wo2T, node_vec, embO, fnode,
                                                  nullptr, nullptr, 0);
    segment_mean<<<NTREES, 256, 0, stream>>>(node_vec, scope_ids, (float*)d_out);
}

// Round 4
// 1279.758 us; speedup vs baseline: 1.9907x; 1.3724x over previous
//
#include <hip/hip_runtime.h>

// JTNN encoder, MI355X.
//  - hU = h @ Ur_w once per row, gathered (5x FLOP cut vs h_nei@Ur)
//  - x-side projections folded into per-VOCAB tables (780 rows, L2-resident)
//  - depth-0 closed form: h1 = sigma(embZ[v]) * tanh(embH[v])  (table lookup)
//  - fused_step: gather + Z-GEMM + P-GEMM + GRU update in ONE kernel;
//    sums live in LDS (no global round-trip), weights in fragment-packed
//    layout so B loads are contiguous 1KiB/wave
//  - standalone hU GEMM: global_load_lds width-16 DMA + XOR-swizzled LDS

#define HD 256
#define NNODES 65536
#define NMESS 131072
#define NVOCAB 780
#define NTREES 2048
#define MAXNEI 5
#define BM 128
#define BMF 64
#define LDF 264   // padded LDS stride (shorts); 528B = 33*16B -> aligned + conflict-free

typedef short bfrag __attribute__((ext_vector_type(8)));   // 8 bf16 in 4 VGPRs
typedef short s16x8 __attribute__((ext_vector_type(8)));
typedef float f32x4v __attribute__((ext_vector_type(4)));
typedef unsigned short ush;

__device__ __forceinline__ float bf2f(ush u) {
    union { unsigned int u; float f; } v; v.u = ((unsigned int)u) << 16; return v.f;
}
__device__ __forceinline__ ush f2bf(float f) {
    union { float f; unsigned int u; } v; v.f = f;
    unsigned int r = v.u + 0x7FFFu + ((v.u >> 16) & 1u);
    return (ush)(r >> 16);
}
__device__ __forceinline__ float sigm(float x) { return 1.f / (1.f + __expf(-x)); }
__device__ __forceinline__ float tanh_fast(float x) {
    float e = __expf(2.f * x); return 1.f - 2.f / (e + 1.f);
}
__device__ __forceinline__ void async16(const ush* g, ush* l) {
    __builtin_amdgcn_global_load_lds(
        (const __attribute__((address_space(1))) unsigned int*)(g),
        (__attribute__((address_space(3))) unsigned int*)(l), 16, 0, 0);
}

// ---------------- prep: vocab tables, split-k over 4 blocks (atomicAdd) -----
__global__ __launch_bounds__(256) void prep_tables_sk(
    const float* __restrict__ emb,
    const float* __restrict__ Wz_w, const float* __restrict__ Wz_b,
    const float* __restrict__ Wr_w, const float* __restrict__ Ur_b,
    const float* __restrict__ Wh_w, const float* __restrict__ Wh_b,
    const float* __restrict__ out_w, const float* __restrict__ out_b,
    float* __restrict__ embR, float* __restrict__ embZ,
    float* __restrict__ embH, float* __restrict__ embO)
{
    __shared__ __align__(16) float e[4][64];
    int t = threadIdx.x;
    int b0 = blockIdx.x * 4;
    int k0 = blockIdx.y * 64;
    e[t >> 6][t & 63] = emb[(b0 + (t >> 6)) * HD + k0 + (t & 63)];
    __syncthreads();
    float aR[4] = {0,0,0,0}, aZ[4] = {0,0,0,0}, aH[4] = {0,0,0,0}, aO[4] = {0,0,0,0};
    for (int kk = 0; kk < 64; kk++) {
        int k = k0 + kk;
        float wr = Wr_w[k * HD + t];
        float wz = Wz_w[k * HD + t];
        float wh = Wh_w[k * HD + t];
        float wo = out_w[k * HD + t];
        #pragma unroll
        for (int r = 0; r < 4; r++) {
            float ev = e[r][kk];
            aR[r] += ev * wr; aZ[r] += ev * wz; aH[r] += ev * wh; aO[r] += ev * wo;
        }
    }
    if (blockIdx.y == 0) {
        float br = Ur_b[t], bz = Wz_b[t], bh = Wh_b[t], bo = out_b[t];
        #pragma unroll
        for (int r = 0; r < 4; r++) { aR[r] += br; aZ[r] += bz; aH[r] += bh; aO[r] += bo; }
    }
    #pragma unroll
    for (int r = 0; r < 4; r++) {
        atomicAdd(&embR[(b0 + r) * HD + t], aR[r]);
        atomicAdd(&embZ[(b0 + r) * HD + t], aZ[r]);
        atomicAdd(&embH[(b0 + r) * HD + t], aH[r]);
        atomicAdd(&embO[(b0 + r) * HD + t], aO[r]);
    }
}

// h1tab[v] = sigmoid(embZ[v]) * tanh(embH[v])   (depth-0 closed form)
__global__ __launch_bounds__(256) void h1fill(
    const float* __restrict__ embZ, const float* __restrict__ embH,
    ush* __restrict__ h1tab)
{
    int i = blockIdx.x * HD + threadIdx.x;
    h1tab[i] = f2bf(sigm(embZ[i]) * tanh_fast(embH[i]));
}

// weights: row-major B^T (UrT, Wo2T) + fragment-packed (Wz_p, Wh_p).
// packed addr for (n,k): f = (n>>4)*8 + (k>>5); lane = ((k>>3)&3)*16 + (n&15);
// elem = (f*64 + lane)*8 + (k&7)  -> fragment load = contiguous 1KiB/wave.
__global__ __launch_bounds__(256) void prep_wt(
    const float* __restrict__ Ur_w, const float* __restrict__ Wz_w,
    const float* __restrict__ Wh_w, const float* __restrict__ out_w,
    ush* __restrict__ UrT, ush* __restrict__ Wo2T,
    ush* __restrict__ Wz_p, ush* __restrict__ Wh_p)
{
    int idx = blockIdx.x * 256 + threadIdx.x;   // n*256 + k
    int n = idx >> 8, k = idx & 255;
    UrT[idx]  = f2bf(Ur_w[k * HD + n]);
    Wo2T[idx] = f2bf(out_w[(HD + k) * HD + n]);
    int paddr = ((((n >> 4) * 8 + (k >> 5)) * 64 + ((k >> 3) & 3) * 16 + (n & 15)) << 3) + (k & 7);
    Wz_p[paddr] = f2bf(Wz_w[(HD + k) * HD + n]);
    Wh_p[paddr] = f2bf(Wh_w[(HD + k) * HD + n]);
}

__global__ __launch_bounds__(256) void prep_vmess(
    const int* __restrict__ fnode, const int* __restrict__ fmess,
    int* __restrict__ v_mess)
{
    int m = blockIdx.x * 256 + threadIdx.x;
    v_mess[m] = fnode[fmess[m]];
}

// depth-0 fill: h[m] = h1tab[v_mess[m]], h[0] = 0   (16B/lane)
__global__ __launch_bounds__(256) void fill_h1(
    const ush* __restrict__ h1tab, const int* __restrict__ v_mess,
    ush* __restrict__ h)
{
    int t = blockIdx.x * 256 + threadIdx.x;
    int m = t >> 5;
    int c = (t & 31) * 8;
    s16x8 o = *(const s16x8*)&h1tab[v_mess[m] * HD + c];
    if (m == 0) o = (s16x8){0, 0, 0, 0, 0, 0, 0, 0};
    *(s16x8*)&h[(size_t)m * HD + c] = o;
}

// ---------------- standalone MFMA GEMM (hU and out-projection) --------------
// BM=128, BN=256 full width, BK=64, 512 threads (2x4 waves, 64x64/wave).
// XOR-swizzled LDS staged by global_load_lds width-16.
// MODE 0: store bf16. MODE 3: relu(acc + embO[vid]) f32.
template<int MODE>
__global__ __launch_bounds__(512) void gemm_tile(
    const ush* __restrict__ A, const ush* __restrict__ Bt,
    void* __restrict__ C,
    const float* __restrict__ etab, const int* __restrict__ vids)
{
    __shared__ __align__(16) ush As[BM * 64];    // 16 KiB
    __shared__ __align__(16) ush Bs[HD * 64];    // 32 KiB
    int tid = threadIdx.x;
    int wave = tid >> 6, lane = tid & 63;
    int wm = wave >> 2, wn = wave & 3;
    int quad = lane >> 4, l16 = lane & 15;
    int row0 = blockIdx.x * BM;

    const ush* aG[2]; ush* aL[2];
    const ush* bG[4]; ush* bL[4];
    #pragma unroll
    for (int u = 0; u < 2; u++) {
        int cch = wave * 2 + u;
        int s = cch * 64 + lane;
        int r = s >> 3, p = s & 7, q = p ^ (r & 7);
        aG[u] = A + (size_t)(row0 + r) * HD + q * 8;
        aL[u] = &As[cch * 512];
    }
    #pragma unroll
    for (int u = 0; u < 4; u++) {
        int cch = wave * 4 + u;
        int s = cch * 64 + lane;
        int r = s >> 3, p = s & 7, q = p ^ (r & 7);
        bG[u] = Bt + (size_t)r * HD + q * 8;
        bL[u] = &Bs[cch * 512];
    }

    f32x4v acc[4][4] = {};

    for (int k0 = 0; k0 < HD; k0 += 64) {
        #pragma unroll
        for (int u = 0; u < 2; u++) async16(aG[u] + k0, aL[u]);
        #pragma unroll
        for (int u = 0; u < 4; u++) async16(bG[u] + k0, bL[u]);
        __syncthreads();
        #pragma unroll
        for (int ks = 0; ks < 64; ks += 32) {
            bfrag af[4], bff[4];
            #pragma unroll
            for (int i = 0; i < 4; i++) {
                int r = wm * 64 + i * 16 + l16;
                int q = (ks >> 3) + quad, p = q ^ (r & 7);
                af[i] = *(const bfrag*)&As[r * 64 + p * 8];
            }
            #pragma unroll
            for (int j = 0; j < 4; j++) {
                int r = wn * 64 + j * 16 + l16;
                int q = (ks >> 3) + quad, p = q ^ (r & 7);
                bff[j] = *(const bfrag*)&Bs[r * 64 + p * 8];
            }
            #pragma unroll
            for (int i = 0; i < 4; i++)
                #pragma unroll
                for (int j = 0; j < 4; j++)
                    acc[i][j] = __builtin_amdgcn_mfma_f32_16x16x32_bf16(af[i], bff[j], acc[i][j], 0, 0, 0);
        }
        __syncthreads();
    }
    #pragma unroll
    for (int i = 0; i < 4; i++) {
        #pragma unroll
        for (int j = 0; j < 4; j++) {
            int Cc = wn * 64 + j * 16 + l16;
            #pragma unroll
            for (int r = 0; r < 4; r++) {
                int Rr = row0 + wm * 64 + i * 16 + quad * 4 + r;
                float v = acc[i][j][r];
                if (MODE == 0) {
                    ((ush*)C)[(size_t)Rr * HD + Cc] = f2bf(v);
                } else {
                    float o = v + etab[vids[Rr] * HD + Cc];
                    ((float*)C)[(size_t)Rr * HD + Cc] = fmaxf(o, 0.f);
                }
            }
        }
    }
}

// ---------------- fused step: gather + Z/P GEMM + GRU update ----------------
// 64 messages/block, 256 threads (4 waves), LDS 66 KiB -> 2 blocks/CU.
__global__ __launch_bounds__(256, 2) void fused_step(
    const ush* __restrict__ h, const ush* __restrict__ hU,
    const int* __restrict__ mg, const int* __restrict__ v_mess,
    const float* __restrict__ embR, const float* __restrict__ embZ,
    const float* __restrict__ embH,
    const ush* __restrict__ Wz_p, const ush* __restrict__ Wh_p,
    ush* __restrict__ h_next)
{
    __shared__ __align__(16) ush sh[BMF * LDF];   // sum_h tile   (33 KiB)
    __shared__ __align__(16) ush sg[BMF * LDF];   // sum_gh tile  (33 KiB)
    int tid = threadIdx.x;
    int wv = tid >> 6, lane = tid & 63;
    int quad = lane >> 4, l16 = lane & 15;
    int m0 = blockIdx.x * BMF;

    // ---- phase 1: gather + r-gate into LDS ----
    #pragma unroll
    for (int it = 0; it < 8; it++) {
        int g = it * 256 + tid;
        int ml = g >> 5;               // 0..63
        int c = (g & 31) * 8;          // 0..248
        int m = m0 + ml;
        int v = v_mess[m];
        float rb[8];
        *(float4*)&rb[0] = *(const float4*)&embR[v * HD + c];
        *(float4*)&rb[4] = *(const float4*)&embR[v * HD + c + 4];
        float ah[8] = {0,0,0,0,0,0,0,0};
        float ag[8] = {0,0,0,0,0,0,0,0};
        #pragma unroll
        for (int kn = 0; kn < MAXNEI; kn++) {
            int j = mg[m * MAXNEI + kn];
            s16x8 hv = *(const s16x8*)&h[(size_t)j * HD + c];
            s16x8 uv = *(const s16x8*)&hU[(size_t)j * HD + c];
            #pragma unroll
            for (int e = 0; e < 8; e++) {
                float hf = bf2f((ush)hv[e]);
                ah[e] += hf;
                ag[e] += sigm(rb[e] + bf2f((ush)uv[e])) * hf;
            }
        }
        s16x8 oh, og;
        #pragma unroll
        for (int e = 0; e < 8; e++) { oh[e] = (short)f2bf(ah[e]); og[e] = (short)f2bf(ag[e]); }
        *(s16x8*)&sh[ml * LDF + c] = oh;
        *(s16x8*)&sg[ml * LDF + c] = og;
    }
    __syncthreads();

    // ---- phase 2: Z = sum_h @ Wz2, P = sum_gh @ Wh2 (B frags from global) ----
    f32x4v az[4][4] = {}, ap[4][4] = {};
    #pragma unroll
    for (int ksi = 0; ksi < 8; ksi++) {
        int ks = ksi * 32;
        bfrag ahf[4], agf[4], bz[4], bh[4];
        #pragma unroll
        for (int i = 0; i < 4; i++) {
            ahf[i] = *(const bfrag*)&sh[(i * 16 + l16) * LDF + ks + quad * 8];
            agf[i] = *(const bfrag*)&sg[(i * 16 + l16) * LDF + ks + quad * 8];
        }
        #pragma unroll
        for (int j = 0; j < 4; j++) {
            int f = ((wv * 4 + j) * 8 + ksi) * 64 + lane;
            bz[j] = *(const bfrag*)&Wz_p[(size_t)f * 8];
            bh[j] = *(const bfrag*)&Wh_p[(size_t)f * 8];
        }
        #pragma unroll
        for (int i = 0; i < 4; i++)
            #pragma unroll
            for (int j = 0; j < 4; j++) {
                az[i][j] = __builtin_amdgcn_mfma_f32_16x16x32_bf16(ahf[i], bz[j], az[i][j], 0, 0, 0);
                ap[i][j] = __builtin_amdgcn_mfma_f32_16x16x32_bf16(agf[i], bh[j], ap[i][j], 0, 0, 0);
            }
    }

    // ---- epilogue: h_next = ((1-z)*sum_h + z*pre) * mask ----
    #pragma unroll
    for (int i = 0; i < 4; i++) {
        #pragma unroll
        for (int j = 0; j < 4; j++) {
            int col = wv * 64 + j * 16 + l16;
            #pragma unroll
            for (int r = 0; r < 4; r++) {
                int rl = i * 16 + quad * 4 + r;
                int Rg = m0 + rl;
                int v = v_mess[Rg];
                float z = sigm(az[i][j][r] + embZ[v * HD + col]);
                float pre = tanh_fast(ap[i][j][r] + embH[v * HD + col]);
                float shv = bf2f(sh[rl * LDF + col]);
                float hn = (1.f - z) * shv + z * pre;
                if (Rg == 0) hn = 0.f;
                h_next[(size_t)Rg * HD + col] = f2bf(hn);
            }
        }
    }
}

// ---------------- node-side neighbor sum (2 nodes/wave, 16B loads) ----------
__global__ __launch_bounds__(256) void gather_nodes(
    const ush* __restrict__ h, const int* __restrict__ ng,
    ush* __restrict__ mess_nei)
{
    int wave = threadIdx.x >> 6, lane = threadIdx.x & 63;
    int half = lane >> 5, li = lane & 31;
    int n = blockIdx.x * 8 + wave * 2 + half;
    int c = li * 8;
    float a[8] = {0,0,0,0,0,0,0,0};
    #pragma unroll
    for (int k = 0; k < MAXNEI; k++) {
        int j = ng[n * MAXNEI + k];
        s16x8 hv = *(const s16x8*)&h[(size_t)j * HD + c];
        #pragma unroll
        for (int e = 0; e < 8; e++) a[e] += bf2f((ush)hv[e]);
    }
    s16x8 o;
    #pragma unroll
    for (int e = 0; e < 8; e++) o[e] = (short)f2bf(a[e]);
    *(s16x8*)&mess_nei[(size_t)n * HD + c] = o;
}

// ---------------- per-tree segment mean (scope_ids sorted) ------------------
__device__ __forceinline__ int lower_bound_dev(const int* a, int n, int key) {
    int lo = 0, hi = n;
    while (lo < hi) { int mid = (lo + hi) >> 1; if (a[mid] < key) lo = mid + 1; else hi = mid; }
    return lo;
}

__global__ __launch_bounds__(256) void segment_mean(
    const float* __restrict__ node_vec, const int* __restrict__ scope,
    float* __restrict__ out)
{
    int t = blockIdx.x;
    int c = threadIdx.x;
    int lo = lower_bound_dev(scope, NNODES, t);
    int hi = lower_bound_dev(scope, NNODES, t + 1);
    float acc = 0.f;
    for (int n = lo; n < hi; n++) acc += node_vec[(size_t)n * HD + c];
    int cnt = hi - lo;
    out[t * HD + c] = cnt > 0 ? acc / (float)cnt : 0.f;
}

// ---------------------------------------------------------------------------
extern "C" void kernel_launch(void* const* d_in, const int* in_sizes, int n_in,
                              void* d_out, int out_size, void* d_ws, size_t ws_size,
                              hipStream_t stream)
{
    const int*   fnode      = (const int*)d_in[0];
    const int*   fmess      = (const int*)d_in[1];
    const int*   node_graph = (const int*)d_in[2];
    const int*   mess_graph = (const int*)d_in[3];
    const int*   scope_ids  = (const int*)d_in[4];
    const float* emb        = (const float*)d_in[5];
    const float* Wz_w       = (const float*)d_in[6];
    const float* Wz_b       = (const float*)d_in[7];
    const float* Wr_w       = (const float*)d_in[8];
    const float* Ur_w       = (const float*)d_in[9];
    const float* Ur_b       = (const float*)d_in[10];
    const float* Wh_w       = (const float*)d_in[11];
    const float* Wh_b       = (const float*)d_in[12];
    const float* out_w      = (const float*)d_in[13];
    const float* out_b      = (const float*)d_in[14];

    // ---- workspace carve (~196.5 MiB) ----
    char* ws = (char*)d_ws;
    const size_t MHB = (size_t)NMESS * HD * 2;         // 64 MiB bf16 full-M
    ush* P0 = (ush*)ws; ws += MHB;                     // h ping
    ush* P1 = (ush*)ws; ws += MHB;                     // h pong
    ush* PU = (ush*)ws; ws += MHB;                     // hU
    float* embR = (float*)ws; ws += (size_t)NVOCAB * HD * 4;
    float* embZ = (float*)ws; ws += (size_t)NVOCAB * HD * 4;
    float* embH = (float*)ws; ws += (size_t)NVOCAB * HD * 4;
    float* embO = (float*)ws; ws += (size_t)NVOCAB * HD * 4;
    ush* h1tab = (ush*)ws; ws += (size_t)NVOCAB * HD * 2;
    ush* UrT   = (ush*)ws; ws += (size_t)HD * HD * 2;
    ush* Wo2T  = (ush*)ws; ws += (size_t)HD * HD * 2;
    ush* Wz_p  = (ush*)ws; ws += (size_t)HD * HD * 2;
    ush* Wh_p  = (ush*)ws; ws += (size_t)HD * HD * 2;
    int* v_mess = (int*)ws; ws += (size_t)NMESS * 4;
    if ((size_t)(ws - (char*)d_ws) > ws_size) return;  // fail loud, not fault

    hipMemsetAsync(embR, 0, (size_t)4 * NVOCAB * HD * 4, stream);
    prep_tables_sk<<<dim3(NVOCAB / 4, 4), 256, 0, stream>>>(
        emb, Wz_w, Wz_b, Wr_w, Ur_b, Wh_w, Wh_b, out_w, out_b,
        embR, embZ, embH, embO);
    h1fill<<<NVOCAB, 256, 0, stream>>>(embZ, embH, h1tab);
    prep_wt<<<HD * HD / 256, 256, 0, stream>>>(Ur_w, Wz_w, Wh_w, out_w,
                                               UrT, Wo2T, Wz_p, Wh_p);
    prep_vmess<<<NMESS / 256, 256, 0, stream>>>(fnode, fmess, v_mess);
    fill_h1<<<NMESS * 32 / 256, 256, 0, stream>>>(h1tab, v_mess, P0);

    ush* hc = P0;
    ush* hn = P1;
    for (int d = 1; d < 6; d++) {
        gemm_tile<0><<<NMESS / BM, 512, 0, stream>>>(hc, UrT, PU, nullptr, nullptr);
        fused_step<<<NMESS / BMF, 256, 0, stream>>>(hc, PU, mess_graph, v_mess,
                                                    embR, embZ, embH, Wz_p, Wh_p, hn);
        ush* tmp = hc; hc = hn; hn = tmp;
    }
    // final h in hc; hn and PU free
    ush* mess_nei = PU;
    float* node_vec = (float*)hn;              // 64 MiB exact fit
    gather_nodes<<<NNODES / 8, 256, 0, stream>>>(hc, node_graph, mess_nei);
    gemm_tile<3><<<NNODES / BM, 512, 0, stream>>>(mess_nei, Wo2T, node_vec, embO, fnode);
    segment_mean<<<NTREES, 256, 0, stream>>>(node_vec, scope_ids, (float*)d_out);
}

// Round 5
// 1190.029 us; speedup vs baseline: 2.1408x; 1.0754x over previous
//
#include <hip/hip_runtime.h>

// JTNN encoder, MI355X.
//  - hU = h @ Ur_w once per row, gathered (5x FLOP cut vs h_nei@Ur)
//  - x-side projections folded into per-VOCAB tables (780 rows, L2-resident)
//  - depth-0 closed form: h1 = sigma(embZ[v]) * tanh(embH[v]); hU1 = (h1tab@Ur)[v]
//  - fused_step: gather + Z/P GEMM + GRU update in ONE kernel; BMF=32 ->
//    33.8 KiB LDS -> 4 blocks/CU (16 waves/CU)
//  - all hot-path divides -> v_rcp_f32; bf16 pack via v_perm (no RNE sequence)

#define HD 256
#define NNODES 65536
#define NMESS 131072
#define NVOCAB 780
#define NTREES 2048
#define MAXNEI 5
#define BM 128
#define BMF 32
#define LDF 264   // padded LDS stride (shorts)

typedef short bfrag __attribute__((ext_vector_type(8)));   // 8 bf16 in 4 VGPRs
typedef short s16x8 __attribute__((ext_vector_type(8)));
typedef float f32x4v __attribute__((ext_vector_type(4)));
typedef unsigned short ush;

__device__ __forceinline__ float bf2f(ush u) {
    union { unsigned int u; float f; } v; v.u = ((unsigned int)u) << 16; return v.f;
}
__device__ __forceinline__ ush f2bf_fast(float f) {
    union { float f; unsigned int u; } v; v.f = f;
    return (ush)((v.u + 0x8000u) >> 16);
}
// pack two f32 -> two bf16 (round-half-up) in one uint via v_perm
__device__ __forceinline__ unsigned int pack2bf(float hi, float lo) {
    union { float f; unsigned int u; } a, b; a.f = hi; b.f = lo;
    return __builtin_amdgcn_perm(a.u + 0x8000u, b.u + 0x8000u, 0x07060302u);
}
__device__ __forceinline__ float sigm(float x) {
    return __builtin_amdgcn_rcpf(1.f + __expf(-x));
}
__device__ __forceinline__ float tanh_fast(float x) {
    return 1.f - 2.f * __builtin_amdgcn_rcpf(__expf(2.f * x) + 1.f);
}
__device__ __forceinline__ void async16(const ush* g, ush* l) {
    __builtin_amdgcn_global_load_lds(
        (const __attribute__((address_space(1))) unsigned int*)(g),
        (__attribute__((address_space(3))) unsigned int*)(l), 16, 0, 0);
}

// ---------------- prep: vocab tables, split-k over 4 blocks (atomicAdd) -----
__global__ __launch_bounds__(256) void prep_tables_sk(
    const float* __restrict__ emb,
    const float* __restrict__ Wz_w, const float* __restrict__ Wz_b,
    const float* __restrict__ Wr_w, const float* __restrict__ Ur_b,
    const float* __restrict__ Wh_w, const float* __restrict__ Wh_b,
    const float* __restrict__ out_w, const float* __restrict__ out_b,
    float* __restrict__ embR, float* __restrict__ embZ,
    float* __restrict__ embH, float* __restrict__ embO)
{
    __shared__ __align__(16) float e[4][64];
    int t = threadIdx.x;
    int b0 = blockIdx.x * 4;
    int k0 = blockIdx.y * 64;
    e[t >> 6][t & 63] = emb[(b0 + (t >> 6)) * HD + k0 + (t & 63)];
    __syncthreads();
    float aR[4] = {0,0,0,0}, aZ[4] = {0,0,0,0}, aH[4] = {0,0,0,0}, aO[4] = {0,0,0,0};
    for (int kk = 0; kk < 64; kk++) {
        int k = k0 + kk;
        float wr = Wr_w[k * HD + t];
        float wz = Wz_w[k * HD + t];
        float wh = Wh_w[k * HD + t];
        float wo = out_w[k * HD + t];
        #pragma unroll
        for (int r = 0; r < 4; r++) {
            float ev = e[r][kk];
            aR[r] += ev * wr; aZ[r] += ev * wz; aH[r] += ev * wh; aO[r] += ev * wo;
        }
    }
    if (blockIdx.y == 0) {
        float br = Ur_b[t], bz = Wz_b[t], bh = Wh_b[t], bo = out_b[t];
        #pragma unroll
        for (int r = 0; r < 4; r++) { aR[r] += br; aZ[r] += bz; aH[r] += bh; aO[r] += bo; }
    }
    #pragma unroll
    for (int r = 0; r < 4; r++) {
        atomicAdd(&embR[(b0 + r) * HD + t], aR[r]);
        atomicAdd(&embZ[(b0 + r) * HD + t], aZ[r]);
        atomicAdd(&embH[(b0 + r) * HD + t], aH[r]);
        atomicAdd(&embO[(b0 + r) * HD + t], aO[r]);
    }
}

// h1tab[v] = sigmoid(embZ[v]) * tanh(embH[v])   (depth-0 closed form)
__global__ __launch_bounds__(256) void h1fill(
    const float* __restrict__ embZ, const float* __restrict__ embH,
    ush* __restrict__ h1tab)
{
    int i = blockIdx.x * HD + threadIdx.x;
    h1tab[i] = f2bf_fast(sigm(embZ[i]) * tanh_fast(embH[i]));
}

// embU[v] = h1tab[v] @ Ur_w  (780x256 rows, split-k atomic)
__global__ __launch_bounds__(256) void h1u_sk(
    const ush* __restrict__ h1tab, const float* __restrict__ Ur_w,
    float* __restrict__ embU)
{
    __shared__ __align__(16) float e[4][64];
    int t = threadIdx.x;
    int b0 = blockIdx.x * 4;
    int k0 = blockIdx.y * 64;
    e[t >> 6][t & 63] = bf2f(h1tab[(b0 + (t >> 6)) * HD + k0 + (t & 63)]);
    __syncthreads();
    float aU[4] = {0,0,0,0};
    for (int kk = 0; kk < 64; kk++) {
        float w = Ur_w[(k0 + kk) * HD + t];
        #pragma unroll
        for (int r = 0; r < 4; r++) aU[r] += e[r][kk] * w;
    }
    #pragma unroll
    for (int r = 0; r < 4; r++) atomicAdd(&embU[(b0 + r) * HD + t], aU[r]);
}

// weights: row-major B^T (UrT, Wo2T) + fragment-packed (Wz_p, Wh_p).
__global__ __launch_bounds__(256) void prep_wt(
    const float* __restrict__ Ur_w, const float* __restrict__ Wz_w,
    const float* __restrict__ Wh_w, const float* __restrict__ out_w,
    ush* __restrict__ UrT, ush* __restrict__ Wo2T,
    ush* __restrict__ Wz_p, ush* __restrict__ Wh_p)
{
    int idx = blockIdx.x * 256 + threadIdx.x;   // n*256 + k
    int n = idx >> 8, k = idx & 255;
    UrT[idx]  = f2bf_fast(Ur_w[k * HD + n]);
    Wo2T[idx] = f2bf_fast(out_w[(HD + k) * HD + n]);
    int paddr = ((((n >> 4) * 8 + (k >> 5)) * 64 + ((k >> 3) & 3) * 16 + (n & 15)) << 3) + (k & 7);
    Wz_p[paddr] = f2bf_fast(Wz_w[(HD + k) * HD + n]);
    Wh_p[paddr] = f2bf_fast(Wh_w[(HD + k) * HD + n]);
}

__global__ __launch_bounds__(256) void prep_vmess(
    const int* __restrict__ fnode, const int* __restrict__ fmess,
    int* __restrict__ v_mess)
{
    int m = blockIdx.x * 256 + threadIdx.x;
    v_mess[m] = fnode[fmess[m]];
}

// depth-0 fill: h[m] = h1tab[v], hU[m] = bf16(embU[v]); row 0 = 0
__global__ __launch_bounds__(256) void fill_h1(
    const ush* __restrict__ h1tab, const float* __restrict__ embU,
    const int* __restrict__ v_mess,
    ush* __restrict__ h, ush* __restrict__ hU)
{
    int t = blockIdx.x * 256 + threadIdx.x;
    int m = t >> 5;
    int c = (t & 31) * 8;
    int v = v_mess[m];
    s16x8 o = *(const s16x8*)&h1tab[v * HD + c];
    float4 u0 = *(const float4*)&embU[v * HD + c];
    float4 u1 = *(const float4*)&embU[v * HD + c + 4];
    uint4 up;
    up.x = pack2bf(u0.y, u0.x); up.y = pack2bf(u0.w, u0.z);
    up.z = pack2bf(u1.y, u1.x); up.w = pack2bf(u1.w, u1.z);
    if (m == 0) { o = (s16x8){0,0,0,0,0,0,0,0}; up.x = up.y = up.z = up.w = 0; }
    *(s16x8*)&h[(size_t)m * HD + c] = o;
    *(uint4*)&hU[(size_t)m * HD + c] = up;
}

// ---------------- standalone MFMA GEMM (hU and out-projection) --------------
// MODE 0: store bf16. MODE 3: relu(acc + embO[vid]) f32.
template<int MODE>
__global__ __launch_bounds__(512) void gemm_tile(
    const ush* __restrict__ A, const ush* __restrict__ Bt,
    void* __restrict__ C,
    const float* __restrict__ etab, const int* __restrict__ vids)
{
    __shared__ __align__(16) ush As[BM * 64];    // 16 KiB
    __shared__ __align__(16) ush Bs[HD * 64];    // 32 KiB
    int tid = threadIdx.x;
    int wave = tid >> 6, lane = tid & 63;
    int wm = wave >> 2, wn = wave & 3;
    int quad = lane >> 4, l16 = lane & 15;
    int row0 = blockIdx.x * BM;

    const ush* aG[2]; ush* aL[2];
    const ush* bG[4]; ush* bL[4];
    #pragma unroll
    for (int u = 0; u < 2; u++) {
        int cch = wave * 2 + u;
        int s = cch * 64 + lane;
        int r = s >> 3, p = s & 7, q = p ^ (r & 7);
        aG[u] = A + (size_t)(row0 + r) * HD + q * 8;
        aL[u] = &As[cch * 512];
    }
    #pragma unroll
    for (int u = 0; u < 4; u++) {
        int cch = wave * 4 + u;
        int s = cch * 64 + lane;
        int r = s >> 3, p = s & 7, q = p ^ (r & 7);
        bG[u] = Bt + (size_t)r * HD + q * 8;
        bL[u] = &Bs[cch * 512];
    }

    f32x4v acc[4][4] = {};

    for (int k0 = 0; k0 < HD; k0 += 64) {
        #pragma unroll
        for (int u = 0; u < 2; u++) async16(aG[u] + k0, aL[u]);
        #pragma unroll
        for (int u = 0; u < 4; u++) async16(bG[u] + k0, bL[u]);
        __syncthreads();
        #pragma unroll
        for (int ks = 0; ks < 64; ks += 32) {
            bfrag af[4], bff[4];
            #pragma unroll
            for (int i = 0; i < 4; i++) {
                int r = wm * 64 + i * 16 + l16;
                int q = (ks >> 3) + quad, p = q ^ (r & 7);
                af[i] = *(const bfrag*)&As[r * 64 + p * 8];
            }
            #pragma unroll
            for (int j = 0; j < 4; j++) {
                int r = wn * 64 + j * 16 + l16;
                int q = (ks >> 3) + quad, p = q ^ (r & 7);
                bff[j] = *(const bfrag*)&Bs[r * 64 + p * 8];
            }
            #pragma unroll
            for (int i = 0; i < 4; i++)
                #pragma unroll
                for (int j = 0; j < 4; j++)
                    acc[i][j] = __builtin_amdgcn_mfma_f32_16x16x32_bf16(af[i], bff[j], acc[i][j], 0, 0, 0);
        }
        __syncthreads();
    }
    #pragma unroll
    for (int i = 0; i < 4; i++) {
        #pragma unroll
        for (int j = 0; j < 4; j++) {
            int Cc = wn * 64 + j * 16 + l16;
            #pragma unroll
            for (int r = 0; r < 4; r++) {
                int Rr = row0 + wm * 64 + i * 16 + quad * 4 + r;
                float v = acc[i][j][r];
                if (MODE == 0) {
                    ((ush*)C)[(size_t)Rr * HD + Cc] = f2bf_fast(v);
                } else {
                    float o = v + etab[vids[Rr] * HD + Cc];
                    ((float*)C)[(size_t)Rr * HD + Cc] = fmaxf(o, 0.f);
                }
            }
        }
    }
}

// ---------------- fused step: gather + Z/P GEMM + GRU update ----------------
// 32 messages/block, 256 threads (4 waves), LDS 33.8 KiB -> 4 blocks/CU.
__global__ __launch_bounds__(256, 4) void fused_step(
    const ush* __restrict__ h, const ush* __restrict__ hU,
    const int* __restrict__ mg, const int* __restrict__ v_mess,
    const float* __restrict__ embR, const float* __restrict__ embZ,
    const float* __restrict__ embH,
    const ush* __restrict__ Wz_p, const ush* __restrict__ Wh_p,
    ush* __restrict__ h_next)
{
    __shared__ __align__(16) ush sh[BMF * LDF];   // sum_h tile   (16.9 KiB)
    __shared__ __align__(16) ush sg[BMF * LDF];   // sum_gh tile
    int tid = threadIdx.x;
    int wv = tid >> 6, lane = tid & 63;
    int quad = lane >> 4, l16 = lane & 15;
    int m0 = blockIdx.x * BMF;

    // ---- phase 1: gather + r-gate into LDS ----
    #pragma unroll 2
    for (int it = 0; it < 4; it++) {
        int g = it * 256 + tid;
        int ml = g >> 5;               // 0..31
        int c = (g & 31) * 8;          // 0..248
        int m = m0 + ml;
        int v = v_mess[m];
        float rb[8];
        *(float4*)&rb[0] = *(const float4*)&embR[v * HD + c];
        *(float4*)&rb[4] = *(const float4*)&embR[v * HD + c + 4];
        float ah[8] = {0,0,0,0,0,0,0,0};
        float ag[8] = {0,0,0,0,0,0,0,0};
        #pragma unroll
        for (int kn = 0; kn < MAXNEI; kn++) {
            int j = mg[m * MAXNEI + kn];
            s16x8 hv = *(const s16x8*)&h[(size_t)j * HD + c];
            s16x8 uv = *(const s16x8*)&hU[(size_t)j * HD + c];
            #pragma unroll
            for (int e = 0; e < 8; e++) {
                float hf = bf2f((ush)hv[e]);
                ah[e] += hf;
                ag[e] += sigm(rb[e] + bf2f((ush)uv[e])) * hf;
            }
        }
        uint4 oh, og;
        oh.x = pack2bf(ah[1], ah[0]); oh.y = pack2bf(ah[3], ah[2]);
        oh.z = pack2bf(ah[5], ah[4]); oh.w = pack2bf(ah[7], ah[6]);
        og.x = pack2bf(ag[1], ag[0]); og.y = pack2bf(ag[3], ag[2]);
        og.z = pack2bf(ag[5], ag[4]); og.w = pack2bf(ag[7], ag[6]);
        *(uint4*)&sh[ml * LDF + c] = oh;
        *(uint4*)&sg[ml * LDF + c] = og;
    }
    __syncthreads();

    // ---- phase 2: Z = sum_h @ Wz2, P = sum_gh @ Wh2 (B frags from global) ----
    f32x4v az[2][4] = {}, ap[2][4] = {};
    #pragma unroll
    for (int ksi = 0; ksi < 8; ksi++) {
        int ks = ksi * 32;
        bfrag ahf[2], agf[2], bz[4], bh[4];
        #pragma unroll
        for (int i = 0; i < 2; i++) {
            ahf[i] = *(const bfrag*)&sh[(i * 16 + l16) * LDF + ks + quad * 8];
            agf[i] = *(const bfrag*)&sg[(i * 16 + l16) * LDF + ks + quad * 8];
        }
        #pragma unroll
        for (int j = 0; j < 4; j++) {
            int f = ((wv * 4 + j) * 8 + ksi) * 64 + lane;
            bz[j] = *(const bfrag*)&Wz_p[(size_t)f * 8];
            bh[j] = *(const bfrag*)&Wh_p[(size_t)f * 8];
        }
        #pragma unroll
        for (int i = 0; i < 2; i++)
            #pragma unroll
            for (int j = 0; j < 4; j++) {
                az[i][j] = __builtin_amdgcn_mfma_f32_16x16x32_bf16(ahf[i], bz[j], az[i][j], 0, 0, 0);
                ap[i][j] = __builtin_amdgcn_mfma_f32_16x16x32_bf16(agf[i], bh[j], ap[i][j], 0, 0, 0);
            }
    }

    // ---- epilogue: h_next = ((1-z)*sum_h + z*pre) * mask ----
    #pragma unroll
    for (int i = 0; i < 2; i++) {
        #pragma unroll
        for (int r = 0; r < 4; r++) {
            int rl = i * 16 + quad * 4 + r;
            int Rg = m0 + rl;
            int v = v_mess[Rg];
            #pragma unroll
            for (int j = 0; j < 4; j++) {
                int col = wv * 64 + j * 16 + l16;
                float z = sigm(az[i][j][r] + embZ[v * HD + col]);
                float pre = tanh_fast(ap[i][j][r] + embH[v * HD + col]);
                float shv = bf2f(sh[rl * LDF + col]);
                float hn = (1.f - z) * shv + z * pre;
                if (Rg == 0) hn = 0.f;
                h_next[(size_t)Rg * HD + col] = f2bf_fast(hn);
            }
        }
    }
}

// ---------------- node-side neighbor sum (2 nodes/wave, 16B loads) ----------
__global__ __launch_bounds__(256) void gather_nodes(
    const ush* __restrict__ h, const int* __restrict__ ng,
    ush* __restrict__ mess_nei)
{
    int wave = threadIdx.x >> 6, lane = threadIdx.x & 63;
    int half = lane >> 5, li = lane & 31;
    int n = blockIdx.x * 8 + wave * 2 + half;
    int c = li * 8;
    float a[8] = {0,0,0,0,0,0,0,0};
    #pragma unroll
    for (int k = 0; k < MAXNEI; k++) {
        int j = ng[n * MAXNEI + k];
        s16x8 hv = *(const s16x8*)&h[(size_t)j * HD + c];
        #pragma unroll
        for (int e = 0; e < 8; e++) a[e] += bf2f((ush)hv[e]);
    }
    uint4 o;
    o.x = pack2bf(a[1], a[0]); o.y = pack2bf(a[3], a[2]);
    o.z = pack2bf(a[5], a[4]); o.w = pack2bf(a[7], a[6]);
    *(uint4*)&mess_nei[(size_t)n * HD + c] = o;
}

// ---------------- per-tree segment mean (scope_ids sorted) ------------------
__device__ __forceinline__ int lower_bound_dev(const int* a, int n, int key) {
    int lo = 0, hi = n;
    while (lo < hi) { int mid = (lo + hi) >> 1; if (a[mid] < key) lo = mid + 1; else hi = mid; }
    return lo;
}

__global__ __launch_bounds__(256) void segment_mean(
    const float* __restrict__ node_vec, const int* __restrict__ scope,
    float* __restrict__ out)
{
    int t = blockIdx.x;
    int c = threadIdx.x;
    int lo = lower_bound_dev(scope, NNODES, t);
    int hi = lower_bound_dev(scope, NNODES, t + 1);
    float acc = 0.f;
    for (int n = lo; n < hi; n++) acc += node_vec[(size_t)n * HD + c];
    int cnt = hi - lo;
    out[t * HD + c] = cnt > 0 ? acc / (float)cnt : 0.f;
}

// ---------------------------------------------------------------------------
extern "C" void kernel_launch(void* const* d_in, const int* in_sizes, int n_in,
                              void* d_out, int out_size, void* d_ws, size_t ws_size,
                              hipStream_t stream)
{
    const int*   fnode      = (const int*)d_in[0];
    const int*   fmess      = (const int*)d_in[1];
    const int*   node_graph = (const int*)d_in[2];
    const int*   mess_graph = (const int*)d_in[3];
    const int*   scope_ids  = (const int*)d_in[4];
    const float* emb        = (const float*)d_in[5];
    const float* Wz_w       = (const float*)d_in[6];
    const float* Wz_b       = (const float*)d_in[7];
    const float* Wr_w       = (const float*)d_in[8];
    const float* Ur_w       = (const float*)d_in[9];
    const float* Ur_b       = (const float*)d_in[10];
    const float* Wh_w       = (const float*)d_in[11];
    const float* Wh_b       = (const float*)d_in[12];
    const float* out_w      = (const float*)d_in[13];
    const float* out_b      = (const float*)d_in[14];

    // ---- workspace carve (~197 MiB) ----
    char* ws = (char*)d_ws;
    const size_t MHB = (size_t)NMESS * HD * 2;         // 64 MiB bf16 full-M
    ush* P0 = (ush*)ws; ws += MHB;                     // h ping
    ush* P1 = (ush*)ws; ws += MHB;                     // h pong
    ush* PU = (ush*)ws; ws += MHB;                     // hU
    float* embR = (float*)ws; ws += (size_t)NVOCAB * HD * 4;
    float* embZ = (float*)ws; ws += (size_t)NVOCAB * HD * 4;
    float* embH = (float*)ws; ws += (size_t)NVOCAB * HD * 4;
    float* embO = (float*)ws; ws += (size_t)NVOCAB * HD * 4;
    float* embU = (float*)ws; ws += (size_t)NVOCAB * HD * 4;
    ush* h1tab = (ush*)ws; ws += (size_t)NVOCAB * HD * 2;
    ush* UrT   = (ush*)ws; ws += (size_t)HD * HD * 2;
    ush* Wo2T  = (ush*)ws; ws += (size_t)HD * HD * 2;
    ush* Wz_p  = (ush*)ws; ws += (size_t)HD * HD * 2;
    ush* Wh_p  = (ush*)ws; ws += (size_t)HD * HD * 2;
    int* v_mess = (int*)ws; ws += (size_t)NMESS * 4;
    if ((size_t)(ws - (char*)d_ws) > ws_size) return;  // fail loud, not fault

    hipMemsetAsync(embR, 0, (size_t)5 * NVOCAB * HD * 4, stream);  // embR..embU
    prep_tables_sk<<<dim3(NVOCAB / 4, 4), 256, 0, stream>>>(
        emb, Wz_w, Wz_b, Wr_w, Ur_b, Wh_w, Wh_b, out_w, out_b,
        embR, embZ, embH, embO);
    h1fill<<<NVOCAB, 256, 0, stream>>>(embZ, embH, h1tab);
    h1u_sk<<<dim3(NVOCAB / 4, 4), 256, 0, stream>>>(h1tab, Ur_w, embU);
    prep_wt<<<HD * HD / 256, 256, 0, stream>>>(Ur_w, Wz_w, Wh_w, out_w,
                                               UrT, Wo2T, Wz_p, Wh_p);
    prep_vmess<<<NMESS / 256, 256, 0, stream>>>(fnode, fmess, v_mess);
    fill_h1<<<NMESS * 32 / 256, 256, 0, stream>>>(h1tab, embU, v_mess, P0, PU);

    ush* hc = P0;
    ush* hn = P1;
    for (int d = 1; d < 6; d++) {
        if (d > 1)
            gemm_tile<0><<<NMESS / BM, 512, 0, stream>>>(hc, UrT, PU, nullptr, nullptr);
        fused_step<<<NMESS / BMF, 256, 0, stream>>>(hc, PU, mess_graph, v_mess,
                                                    embR, embZ, embH, Wz_p, Wh_p, hn);
        ush* tmp = hc; hc = hn; hn = tmp;
    }
    // final h in hc; hn and PU free
    ush* mess_nei = PU;
    float* node_vec = (float*)hn;              // 64 MiB exact fit
    gather_nodes<<<NNODES / 8, 256, 0, stream>>>(hc, node_graph, mess_nei);
    gemm_tile<3><<<NNODES / BM, 512, 0, stream>>>(mess_nei, Wo2T, node_vec, embO, fnode);
    segment_mean<<<NTREES, 256, 0, stream>>>(node_vec, scope_ids, (float*)d_out);
}

// Round 6
// 1086.959 us; speedup vs baseline: 2.3438x; 1.0948x over previous
//
#include <hip/hip_runtime.h>

// JTNN encoder, MI355X.
//  - hU = h @ Ur_w once per row, gathered (5x FLOP cut vs h_nei@Ur)
//  - hU stored fp8 e4m3 (HW cvt): halves gather traffic, LLC-resident set
//  - x-side projections folded into per-VOCAB tables (780 rows, L2-resident)
//  - depth-0 closed form: h1 = sigma(embZ[v]) * tanh(embH[v]); hU1 = (h1tab@Ur)[v]
//  - fused_step: gather + Z/P GEMM + GRU update + U-GEMM (hU_next) in ONE
//    kernel; h_next/hU_next written coalesced via LDS round-trip

#define HD 256
#define NNODES 65536
#define NMESS 131072
#define NVOCAB 780
#define NTREES 2048
#define MAXNEI 5
#define BM 128
#define BMF 32
#define LDF 264   // padded LDS stride (shorts)

typedef short bfrag __attribute__((ext_vector_type(8)));   // 8 bf16 in 4 VGPRs
typedef short s16x8 __attribute__((ext_vector_type(8)));
typedef float f32x4v __attribute__((ext_vector_type(4)));
typedef float f32x2 __attribute__((ext_vector_type(2)));
typedef unsigned short ush;
typedef unsigned char u8;

__device__ __forceinline__ float bf2f(ush u) {
    union { unsigned int u; float f; } v; v.u = ((unsigned int)u) << 16; return v.f;
}
__device__ __forceinline__ float bfu_lo(unsigned int w) {
    union { unsigned int u; float f; } v; v.u = w << 16; return v.f;
}
__device__ __forceinline__ float bfu_hi(unsigned int w) {
    union { unsigned int u; float f; } v; v.u = w & 0xffff0000u; return v.f;
}
__device__ __forceinline__ ush f2bf_fast(float f) {
    union { float f; unsigned int u; } v; v.f = f;
    return (ush)((v.u + 0x8000u) >> 16);
}
// pack two f32 -> two bf16 (round-half-up) in one uint via v_perm
__device__ __forceinline__ unsigned int pack2bf(float hi, float lo) {
    union { float f; unsigned int u; } a, b; a.f = hi; b.f = lo;
    return __builtin_amdgcn_perm(a.u + 0x8000u, b.u + 0x8000u, 0x07060302u);
}
__device__ __forceinline__ float sigm(float x) {
    return __builtin_amdgcn_rcpf(1.f + __expf(-x));
}
__device__ __forceinline__ float tanh_fast(float x) {
    return 1.f - 2.f * __builtin_amdgcn_rcpf(__expf(2.f * x) + 1.f);
}
__device__ __forceinline__ void async16(const ush* g, ush* l) {
    __builtin_amdgcn_global_load_lds(
        (const __attribute__((address_space(1))) unsigned int*)(g),
        (__attribute__((address_space(3))) unsigned int*)(l), 16, 0, 0);
}
// 8 f32 -> 8 fp8 e4m3 packed in uint2
__device__ __forceinline__ uint2 pack8fp8(const float* f) {
    int lo = __builtin_amdgcn_cvt_pk_fp8_f32(f[0], f[1], 0, 0);
    lo = __builtin_amdgcn_cvt_pk_fp8_f32(f[2], f[3], lo, 1);
    int hi = __builtin_amdgcn_cvt_pk_fp8_f32(f[4], f[5], 0, 0);
    hi = __builtin_amdgcn_cvt_pk_fp8_f32(f[6], f[7], hi, 1);
    uint2 o; o.x = (unsigned int)lo; o.y = (unsigned int)hi; return o;
}

// ---------------- prep: vocab tables, split-k over 4 blocks (atomicAdd) -----
__global__ __launch_bounds__(256) void prep_tables_sk(
    const float* __restrict__ emb,
    const float* __restrict__ Wz_w, const float* __restrict__ Wz_b,
    const float* __restrict__ Wr_w, const float* __restrict__ Ur_b,
    const float* __restrict__ Wh_w, const float* __restrict__ Wh_b,
    const float* __restrict__ out_w, const float* __restrict__ out_b,
    float* __restrict__ embR, float* __restrict__ embZ,
    float* __restrict__ embH, float* __restrict__ embO)
{
    __shared__ __align__(16) float e[4][64];
    int t = threadIdx.x;
    int b0 = blockIdx.x * 4;
    int k0 = blockIdx.y * 64;
    e[t >> 6][t & 63] = emb[(b0 + (t >> 6)) * HD + k0 + (t & 63)];
    __syncthreads();
    float aR[4] = {0,0,0,0}, aZ[4] = {0,0,0,0}, aH[4] = {0,0,0,0}, aO[4] = {0,0,0,0};
    for (int kk = 0; kk < 64; kk++) {
        int k = k0 + kk;
        float wr = Wr_w[k * HD + t];
        float wz = Wz_w[k * HD + t];
        float wh = Wh_w[k * HD + t];
        float wo = out_w[k * HD + t];
        #pragma unroll
        for (int r = 0; r < 4; r++) {
            float ev = e[r][kk];
            aR[r] += ev * wr; aZ[r] += ev * wz; aH[r] += ev * wh; aO[r] += ev * wo;
        }
    }
    if (blockIdx.y == 0) {
        float br = Ur_b[t], bz = Wz_b[t], bh = Wh_b[t], bo = out_b[t];
        #pragma unroll
        for (int r = 0; r < 4; r++) { aR[r] += br; aZ[r] += bz; aH[r] += bh; aO[r] += bo; }
    }
    #pragma unroll
    for (int r = 0; r < 4; r++) {
        atomicAdd(&embR[(b0 + r) * HD + t], aR[r]);
        atomicAdd(&embZ[(b0 + r) * HD + t], aZ[r]);
        atomicAdd(&embH[(b0 + r) * HD + t], aH[r]);
        atomicAdd(&embO[(b0 + r) * HD + t], aO[r]);
    }
}

// h1tab[v] = sigmoid(embZ[v]) * tanh(embH[v])   (depth-0 closed form)
__global__ __launch_bounds__(256) void h1fill(
    const float* __restrict__ embZ, const float* __restrict__ embH,
    ush* __restrict__ h1tab)
{
    int i = blockIdx.x * HD + threadIdx.x;
    h1tab[i] = f2bf_fast(sigm(embZ[i]) * tanh_fast(embH[i]));
}

// embU[v] = h1tab[v] @ Ur_w  (780x256 rows, split-k atomic)
__global__ __launch_bounds__(256) void h1u_sk(
    const ush* __restrict__ h1tab, const float* __restrict__ Ur_w,
    float* __restrict__ embU)
{
    __shared__ __align__(16) float e[4][64];
    int t = threadIdx.x;
    int b0 = blockIdx.x * 4;
    int k0 = blockIdx.y * 64;
    e[t >> 6][t & 63] = bf2f(h1tab[(b0 + (t >> 6)) * HD + k0 + (t & 63)]);
    __syncthreads();
    float aU[4] = {0,0,0,0};
    for (int kk = 0; kk < 64; kk++) {
        float w = Ur_w[(k0 + kk) * HD + t];
        #pragma unroll
        for (int r = 0; r < 4; r++) aU[r] += e[r][kk] * w;
    }
    #pragma unroll
    for (int r = 0; r < 4; r++) atomicAdd(&embU[(b0 + r) * HD + t], aU[r]);
}

// weights: row-major B^T (Wo2T) + fragment-packed (Wz_p, Wh_p, Ur_p).
// packed addr for (n,k): f = (n>>4)*8 + (k>>5); lane = ((k>>3)&3)*16 + (n&15);
// elem = (f*64 + lane)*8 + (k&7)  -> fragment load = contiguous 1KiB/wave.
__global__ __launch_bounds__(256) void prep_wt(
    const float* __restrict__ Ur_w, const float* __restrict__ Wz_w,
    const float* __restrict__ Wh_w, const float* __restrict__ out_w,
    ush* __restrict__ Wo2T,
    ush* __restrict__ Wz_p, ush* __restrict__ Wh_p, ush* __restrict__ Ur_p)
{
    int idx = blockIdx.x * 256 + threadIdx.x;   // n*256 + k
    int n = idx >> 8, k = idx & 255;
    Wo2T[idx] = f2bf_fast(out_w[(HD + k) * HD + n]);
    int paddr = ((((n >> 4) * 8 + (k >> 5)) * 64 + ((k >> 3) & 3) * 16 + (n & 15)) << 3) + (k & 7);
    Wz_p[paddr] = f2bf_fast(Wz_w[(HD + k) * HD + n]);
    Wh_p[paddr] = f2bf_fast(Wh_w[(HD + k) * HD + n]);
    Ur_p[paddr] = f2bf_fast(Ur_w[k * HD + n]);
}

__global__ __launch_bounds__(256) void prep_vmess(
    const int* __restrict__ fnode, const int* __restrict__ fmess,
    int* __restrict__ v_mess)
{
    int m = blockIdx.x * 256 + threadIdx.x;
    v_mess[m] = fnode[fmess[m]];
}

// depth-0 fill: h[m] = h1tab[v], hU8[m] = fp8(embU[v]); row 0 = 0
__global__ __launch_bounds__(256) void fill_h1(
    const ush* __restrict__ h1tab, const float* __restrict__ embU,
    const int* __restrict__ v_mess,
    ush* __restrict__ h, u8* __restrict__ hU8)
{
    int t = blockIdx.x * 256 + threadIdx.x;
    int m = t >> 5;
    int c = (t & 31) * 8;
    int v = v_mess[m];
    s16x8 o = *(const s16x8*)&h1tab[v * HD + c];
    float u[8];
    *(float4*)&u[0] = *(const float4*)&embU[v * HD + c];
    *(float4*)&u[4] = *(const float4*)&embU[v * HD + c + 4];
    uint2 up = pack8fp8(u);
    if (m == 0) { o = (s16x8){0,0,0,0,0,0,0,0}; up.x = up.y = 0; }
    *(s16x8*)&h[(size_t)m * HD + c] = o;
    *(uint2*)&hU8[(size_t)m * HD + c] = up;
}

// ---------------- standalone MFMA GEMM (out-projection only) ----------------
__global__ __launch_bounds__(512) void gemm_out(
    const ush* __restrict__ A, const ush* __restrict__ Bt,
    float* __restrict__ C,
    const float* __restrict__ etab, const int* __restrict__ vids)
{
    __shared__ __align__(16) ush As[BM * 64];    // 16 KiB
    __shared__ __align__(16) ush Bs[HD * 64];    // 32 KiB
    int tid = threadIdx.x;
    int wave = tid >> 6, lane = tid & 63;
    int wm = wave >> 2, wn = wave & 3;
    int quad = lane >> 4, l16 = lane & 15;
    int row0 = blockIdx.x * BM;

    const ush* aG[2]; ush* aL[2];
    const ush* bG[4]; ush* bL[4];
    #pragma unroll
    for (int u = 0; u < 2; u++) {
        int cch = wave * 2 + u;
        int s = cch * 64 + lane;
        int r = s >> 3, p = s & 7, q = p ^ (r & 7);
        aG[u] = A + (size_t)(row0 + r) * HD + q * 8;
        aL[u] = &As[cch * 512];
    }
    #pragma unroll
    for (int u = 0; u < 4; u++) {
        int cch = wave * 4 + u;
        int s = cch * 64 + lane;
        int r = s >> 3, p = s & 7, q = p ^ (r & 7);
        bG[u] = Bt + (size_t)r * HD + q * 8;
        bL[u] = &Bs[cch * 512];
    }

    f32x4v acc[4][4] = {};

    for (int k0 = 0; k0 < HD; k0 += 64) {
        #pragma unroll
        for (int u = 0; u < 2; u++) async16(aG[u] + k0, aL[u]);
        #pragma unroll
        for (int u = 0; u < 4; u++) async16(bG[u] + k0, bL[u]);
        __syncthreads();
        #pragma unroll
        for (int ks = 0; ks < 64; ks += 32) {
            bfrag af[4], bff[4];
            #pragma unroll
            for (int i = 0; i < 4; i++) {
                int r = wm * 64 + i * 16 + l16;
                int q = (ks >> 3) + quad, p = q ^ (r & 7);
                af[i] = *(const bfrag*)&As[r * 64 + p * 8];
            }
            #pragma unroll
            for (int j = 0; j < 4; j++) {
                int r = wn * 64 + j * 16 + l16;
                int q = (ks >> 3) + quad, p = q ^ (r & 7);
                bff[j] = *(const bfrag*)&Bs[r * 64 + p * 8];
            }
            #pragma unroll
            for (int i = 0; i < 4; i++)
                #pragma unroll
                for (int j = 0; j < 4; j++)
                    acc[i][j] = __builtin_amdgcn_mfma_f32_16x16x32_bf16(af[i], bff[j], acc[i][j], 0, 0, 0);
        }
        __syncthreads();
    }
    #pragma unroll
    for (int i = 0; i < 4; i++) {
        #pragma unroll
        for (int j = 0; j < 4; j++) {
            int Cc = wn * 64 + j * 16 + l16;
            #pragma unroll
            for (int r = 0; r < 4; r++) {
                int Rr = row0 + wm * 64 + i * 16 + quad * 4 + r;
                float o = acc[i][j][r] + etab[vids[Rr] * HD + Cc];
                C[(size_t)Rr * HD + Cc] = fmaxf(o, 0.f);
            }
        }
    }
}

// ---------------- fused step: gather + Z/P GEMM + GRU + U-GEMM --------------
// 32 messages/block, 256 threads (4 waves), LDS 33.8 KiB -> 4 blocks/CU.
template<int EMIT_HU>
__global__ __launch_bounds__(256, 4) void fused_step(
    const ush* __restrict__ h, const u8* __restrict__ hU8,
    const int* __restrict__ mg, const int* __restrict__ v_mess,
    const float* __restrict__ embR, const float* __restrict__ embZ,
    const float* __restrict__ embH,
    const ush* __restrict__ Wz_p, const ush* __restrict__ Wh_p,
    const ush* __restrict__ Ur_p,
    ush* __restrict__ h_next, u8* __restrict__ hU8_next)
{
    __shared__ __align__(16) ush sh[BMF * LDF];   // sum_h tile  (16.9 KiB)
    __shared__ __align__(16) ush sg[BMF * LDF];   // sum_gh tile -> h_next tile
    int tid = threadIdx.x;
    int wv = tid >> 6, lane = tid & 63;
    int quad = lane >> 4, l16 = lane & 15;
    int m0 = blockIdx.x * BMF;

    // ---- phase 1: gather + r-gate into LDS ----
    #pragma unroll 2
    for (int it = 0; it < 4; it++) {
        int g = it * 256 + tid;
        int ml = g >> 5;               // 0..31
        int c = (g & 31) * 8;          // 0..248
        int m = m0 + ml;
        int v = v_mess[m];
        float rb[8];
        *(float4*)&rb[0] = *(const float4*)&embR[v * HD + c];
        *(float4*)&rb[4] = *(const float4*)&embR[v * HD + c + 4];
        float ah[8] = {0,0,0,0,0,0,0,0};
        float ag[8] = {0,0,0,0,0,0,0,0};
        #pragma unroll
        for (int kn = 0; kn < MAXNEI; kn++) {
            int j = mg[m * MAXNEI + kn];
            s16x8 hv = *(const s16x8*)&h[(size_t)j * HD + c];
            uint2 uv = *(const uint2*)&hU8[(size_t)j * HD + c];
            f32x2 u01 = __builtin_amdgcn_cvt_pk_f32_fp8((int)uv.x, false);
            f32x2 u23 = __builtin_amdgcn_cvt_pk_f32_fp8((int)uv.x, true);
            f32x2 u45 = __builtin_amdgcn_cvt_pk_f32_fp8((int)uv.y, false);
            f32x2 u67 = __builtin_amdgcn_cvt_pk_f32_fp8((int)uv.y, true);
            float uf[8] = {u01.x, u01.y, u23.x, u23.y, u45.x, u45.y, u67.x, u67.y};
            #pragma unroll
            for (int e = 0; e < 8; e++) {
                float hf = bf2f((ush)hv[e]);
                ah[e] += hf;
                ag[e] += sigm(rb[e] + uf[e]) * hf;
            }
        }
        uint4 oh, og;
        oh.x = pack2bf(ah[1], ah[0]); oh.y = pack2bf(ah[3], ah[2]);
        oh.z = pack2bf(ah[5], ah[4]); oh.w = pack2bf(ah[7], ah[6]);
        og.x = pack2bf(ag[1], ag[0]); og.y = pack2bf(ag[3], ag[2]);
        og.z = pack2bf(ag[5], ag[4]); og.w = pack2bf(ag[7], ag[6]);
        *(uint4*)&sh[ml * LDF + c] = oh;
        *(uint4*)&sg[ml * LDF + c] = og;
    }
    __syncthreads();

    // ---- phase 2: Z = sum_h @ Wz2, P = sum_gh @ Wh2 (B frags from global) ----
    f32x4v az[2][4] = {}, ap[2][4] = {};
    #pragma unroll
    for (int ksi = 0; ksi < 8; ksi++) {
        int ks = ksi * 32;
        bfrag ahf[2], agf[2], bz[4], bh[4];
        #pragma unroll
        for (int i = 0; i < 2; i++) {
            ahf[i] = *(const bfrag*)&sh[(i * 16 + l16) * LDF + ks + quad * 8];
            agf[i] = *(const bfrag*)&sg[(i * 16 + l16) * LDF + ks + quad * 8];
        }
        #pragma unroll
        for (int j = 0; j < 4; j++) {
            int f = ((wv * 4 + j) * 8 + ksi) * 64 + lane;
            bz[j] = *(const bfrag*)&Wz_p[(size_t)f * 8];
            bh[j] = *(const bfrag*)&Wh_p[(size_t)f * 8];
        }
        #pragma unroll
        for (int i = 0; i < 2; i++)
            #pragma unroll
            for (int j = 0; j < 4; j++) {
                az[i][j] = __builtin_amdgcn_mfma_f32_16x16x32_bf16(ahf[i], bz[j], az[i][j], 0, 0, 0);
                ap[i][j] = __builtin_amdgcn_mfma_f32_16x16x32_bf16(agf[i], bh[j], ap[i][j], 0, 0, 0);
            }
    }

    // ---- GRU combine: az[i][j][r] <- h_next value (reuse regs) ----
    #pragma unroll
    for (int i = 0; i < 2; i++) {
        #pragma unroll
        for (int r = 0; r < 4; r++) {
            int rl = i * 16 + quad * 4 + r;
            int Rg = m0 + rl;
            int v = v_mess[Rg];
            #pragma unroll
            for (int j = 0; j < 4; j++) {
                int col = wv * 64 + j * 16 + l16;
                float z = sigm(az[i][j][r] + embZ[v * HD + col]);
                float pre = tanh_fast(ap[i][j][r] + embH[v * HD + col]);
                float shv = bf2f(sh[rl * LDF + col]);
                float hn = (1.f - z) * shv + z * pre;
                if (Rg == 0) hn = 0.f;
                az[i][j][r] = hn;
            }
        }
    }
    __syncthreads();   // all sh/sg reads done

    // ---- write h_next tile into sg (LDS), then coalesced global write ----
    #pragma unroll
    for (int i = 0; i < 2; i++)
        #pragma unroll
        for (int j = 0; j < 4; j++) {
            int col = wv * 64 + j * 16 + l16;
            #pragma unroll
            for (int r = 0; r < 4; r++)
                sg[(i * 16 + quad * 4 + r) * LDF + col] = f2bf_fast(az[i][j][r]);
        }
    __syncthreads();
    #pragma unroll
    for (int it = 0; it < 4; it++) {
        int g = it * 256 + tid;
        int ml = g >> 5;
        int c = (g & 31) * 8;
        *(uint4*)&h_next[(size_t)(m0 + ml) * HD + c] = *(const uint4*)&sg[ml * LDF + c];
    }

    if (EMIT_HU) {
        // ---- U-GEMM: hU_next = h_next @ Ur  (A frags from sg) ----
        f32x4v au[2][4] = {};
        #pragma unroll
        for (int ksi = 0; ksi < 8; ksi++) {
            int ks = ksi * 32;
            bfrag af[2], bu[4];
            #pragma unroll
            for (int i = 0; i < 2; i++)
                af[i] = *(const bfrag*)&sg[(i * 16 + l16) * LDF + ks + quad * 8];
            #pragma unroll
            for (int j = 0; j < 4; j++) {
                int f = ((wv * 4 + j) * 8 + ksi) * 64 + lane;
                bu[j] = *(const bfrag*)&Ur_p[(size_t)f * 8];
            }
            #pragma unroll
            for (int i = 0; i < 2; i++)
                #pragma unroll
                for (int j = 0; j < 4; j++)
                    au[i][j] = __builtin_amdgcn_mfma_f32_16x16x32_bf16(af[i], bu[j], au[i][j], 0, 0, 0);
        }
        // write au (bf16) into sh, then coalesced fp8 pack + store
        #pragma unroll
        for (int i = 0; i < 2; i++)
            #pragma unroll
            for (int j = 0; j < 4; j++) {
                int col = wv * 64 + j * 16 + l16;
                #pragma unroll
                for (int r = 0; r < 4; r++)
                    sh[(i * 16 + quad * 4 + r) * LDF + col] = f2bf_fast(au[i][j][r]);
            }
        __syncthreads();
        #pragma unroll
        for (int it = 0; it < 4; it++) {
            int g = it * 256 + tid;
            int ml = g >> 5;
            int c = (g & 31) * 8;
            uint4 w = *(const uint4*)&sh[ml * LDF + c];
            float f[8] = { bfu_lo(w.x), bfu_hi(w.x), bfu_lo(w.y), bfu_hi(w.y),
                           bfu_lo(w.z), bfu_hi(w.z), bfu_lo(w.w), bfu_hi(w.w) };
            uint2 o = pack8fp8(f);
            *(uint2*)&hU8_next[(size_t)(m0 + ml) * HD + c] = o;
        }
    }
}

// ---------------- node-side neighbor sum (2 nodes/wave, 16B loads) ----------
__global__ __launch_bounds__(256) void gather_nodes(
    const ush* __restrict__ h, const int* __restrict__ ng,
    ush* __restrict__ mess_nei)
{
    int wave = threadIdx.x >> 6, lane = threadIdx.x & 63;
    int half = lane >> 5, li = lane & 31;
    int n = blockIdx.x * 8 + wave * 2 + half;
    int c = li * 8;
    float a[8] = {0,0,0,0,0,0,0,0};
    #pragma unroll
    for (int k = 0; k < MAXNEI; k++) {
        int j = ng[n * MAXNEI + k];
        s16x8 hv = *(const s16x8*)&h[(size_t)j * HD + c];
        #pragma unroll
        for (int e = 0; e < 8; e++) a[e] += bf2f((ush)hv[e]);
    }
    uint4 o;
    o.x = pack2bf(a[1], a[0]); o.y = pack2bf(a[3], a[2]);
    o.z = pack2bf(a[5], a[4]); o.w = pack2bf(a[7], a[6]);
    *(uint4*)&mess_nei[(size_t)n * HD + c] = o;
}

// ---------------- per-tree segment mean (scope_ids sorted) ------------------
__device__ __forceinline__ int lower_bound_dev(const int* a, int n, int key) {
    int lo = 0, hi = n;
    while (lo < hi) { int mid = (lo + hi) >> 1; if (a[mid] < key) lo = mid + 1; else hi = mid; }
    return lo;
}

__global__ __launch_bounds__(256) void segment_mean(
    const float* __restrict__ node_vec, const int* __restrict__ scope,
    float* __restrict__ out)
{
    int t = blockIdx.x;
    int c = threadIdx.x;
    int lo = lower_bound_dev(scope, NNODES, t);
    int hi = lower_bound_dev(scope, NNODES, t + 1);
    float acc = 0.f;
    for (int n = lo; n < hi; n++) acc += node_vec[(size_t)n * HD + c];
    int cnt = hi - lo;
    out[t * HD + c] = cnt > 0 ? acc / (float)cnt : 0.f;
}

// ---------------------------------------------------------------------------
extern "C" void kernel_launch(void* const* d_in, const int* in_sizes, int n_in,
                              void* d_out, int out_size, void* d_ws, size_t ws_size,
                              hipStream_t stream)
{
    const int*   fnode      = (const int*)d_in[0];
    const int*   fmess      = (const int*)d_in[1];
    const int*   node_graph = (const int*)d_in[2];
    const int*   mess_graph = (const int*)d_in[3];
    const int*   scope_ids  = (const int*)d_in[4];
    const float* emb        = (const float*)d_in[5];
    const float* Wz_w       = (const float*)d_in[6];
    const float* Wz_b       = (const float*)d_in[7];
    const float* Wr_w       = (const float*)d_in[8];
    const float* Ur_w       = (const float*)d_in[9];
    const float* Ur_b       = (const float*)d_in[10];
    const float* Wh_w       = (const float*)d_in[11];
    const float* Wh_b       = (const float*)d_in[12];
    const float* out_w      = (const float*)d_in[13];
    const float* out_b      = (const float*)d_in[14];

    // ---- workspace carve (~200 MiB) ----
    char* ws = (char*)d_ws;
    const size_t MHB = (size_t)NMESS * HD * 2;         // 64 MiB bf16 full-M
    const size_t MH8 = (size_t)NMESS * HD;             // 32 MiB fp8 full-M
    ush* P0 = (ush*)ws; ws += MHB;                     // h ping
    ush* P1 = (ush*)ws; ws += MHB;                     // h pong
    u8* U0 = (u8*)ws; ws += MH8;                       // hU8 ping
    u8* U1 = (u8*)ws; ws += MH8;                       // hU8 pong
    float* embR = (float*)ws; ws += (size_t)NVOCAB * HD * 4;
    float* embZ = (float*)ws; ws += (size_t)NVOCAB * HD * 4;
    float* embH = (float*)ws; ws += (size_t)NVOCAB * HD * 4;
    float* embO = (float*)ws; ws += (size_t)NVOCAB * HD * 4;
    float* embU = (float*)ws; ws += (size_t)NVOCAB * HD * 4;
    ush* h1tab = (ush*)ws; ws += (size_t)NVOCAB * HD * 2;
    ush* Wo2T  = (ush*)ws; ws += (size_t)HD * HD * 2;
    ush* Wz_p  = (ush*)ws; ws += (size_t)HD * HD * 2;
    ush* Wh_p  = (ush*)ws; ws += (size_t)HD * HD * 2;
    ush* Ur_p  = (ush*)ws; ws += (size_t)HD * HD * 2;
    int* v_mess = (int*)ws; ws += (size_t)NMESS * 4;
    if ((size_t)(ws - (char*)d_ws) > ws_size) return;  // fail loud, not fault

    hipMemsetAsync(embR, 0, (size_t)5 * NVOCAB * HD * 4, stream);  // embR..embU
    prep_tables_sk<<<dim3(NVOCAB / 4, 4), 256, 0, stream>>>(
        emb, Wz_w, Wz_b, Wr_w, Ur_b, Wh_w, Wh_b, out_w, out_b,
        embR, embZ, embH, embO);
    h1fill<<<NVOCAB, 256, 0, stream>>>(embZ, embH, h1tab);
    h1u_sk<<<dim3(NVOCAB / 4, 4), 256, 0, stream>>>(h1tab, Ur_w, embU);
    prep_wt<<<HD * HD / 256, 256, 0, stream>>>(Ur_w, Wz_w, Wh_w, out_w,
                                               Wo2T, Wz_p, Wh_p, Ur_p);
    prep_vmess<<<NMESS / 256, 256, 0, stream>>>(fnode, fmess, v_mess);
    fill_h1<<<NMESS * 32 / 256, 256, 0, stream>>>(h1tab, embU, v_mess, P0, U0);

    ush* hc = P0; ush* hn = P1;
    u8* uc = U0; u8* un = U1;
    for (int d = 1; d < 5; d++) {
        fused_step<1><<<NMESS / BMF, 256, 0, stream>>>(hc, uc, mess_graph, v_mess,
                                                       embR, embZ, embH,
                                                       Wz_p, Wh_p, Ur_p, hn, un);
        { ush* t = hc; hc = hn; hn = t; }
        { u8* t = uc; uc = un; un = t; }
    }
    fused_step<0><<<NMESS / BMF, 256, 0, stream>>>(hc, uc, mess_graph, v_mess,
                                                   embR, embZ, embH,
                                                   Wz_p, Wh_p, Ur_p, hn, nullptr);
    hc = hn;  // final h; the other h buffer + both hU8 buffers are free

    ush* mess_nei = (ush*)U0;                  // 33.5 MB fits in U0 (32 MiB)+U1 head
    float* node_vec = (float*)(hc == P0 ? P1 : P0);   // 64 MiB exact fit
    gather_nodes<<<NNODES / 8, 256, 0, stream>>>(hc, node_graph, mess_nei);
    gemm_out<<<NNODES / BM, 512, 0, stream>>>(mess_nei, Wo2T, node_vec, embO, fnode);
    segment_mean<<<NTREES, 256, 0, stream>>>(node_vec, scope_ids, (float*)d_out);
}

// Round 8
// 1077.040 us; speedup vs baseline: 2.3654x; 1.0092x over previous
//
#include <hip/hip_runtime.h>

// JTNN encoder, MI355X.
//  - hU = h @ Ur_w once per row, gathered (5x FLOP cut vs h_nei@Ur)
//  - h bf16 (fp8-h FAILED accuracy: (1-z)*sum_h passes quantization noise
//    linearly, compounds over depth -> absmax 7.5 > 5.04). hU fp8 e4m3 is
//    validated safe (enters only via sigmoid).
//  - x-side projections folded into per-VOCAB tables (780 rows, L2-resident)
//  - depth-0 closed form: h1 = sigma(embZ[v]) * tanh(embH[v]); hU1 = (h1tab@Ur)[v]
//  - fused_step: gather + Z/P GEMM + GRU update + U-GEMM (hU_next) in ONE kernel
//  - gather_out: node-side gather + out-projection GEMM fused (kills mess_nei
//    round-trip)

#define HD 256
#define NNODES 65536
#define NMESS 131072
#define NVOCAB 780
#define NTREES 2048
#define MAXNEI 5
#define BMF 32
#define LDF 264   // padded LDS stride (shorts)

typedef short bfrag __attribute__((ext_vector_type(8)));   // 8 bf16 in 4 VGPRs
typedef short s16x8 __attribute__((ext_vector_type(8)));
typedef float f32x4v __attribute__((ext_vector_type(4)));
typedef float f32x2 __attribute__((ext_vector_type(2)));
typedef unsigned short ush;
typedef unsigned char u8;

__device__ __forceinline__ float bf2f(ush u) {
    union { unsigned int u; float f; } v; v.u = ((unsigned int)u) << 16; return v.f;
}
__device__ __forceinline__ float bfu_lo(unsigned int w) {
    union { unsigned int u; float f; } v; v.u = w << 16; return v.f;
}
__device__ __forceinline__ float bfu_hi(unsigned int w) {
    union { unsigned int u; float f; } v; v.u = w & 0xffff0000u; return v.f;
}
__device__ __forceinline__ ush f2bf_fast(float f) {
    union { float f; unsigned int u; } v; v.f = f;
    return (ush)((v.u + 0x8000u) >> 16);
}
// pack two f32 -> two bf16 (round-half-up) in one uint via v_perm
__device__ __forceinline__ unsigned int pack2bf(float hi, float lo) {
    union { float f; unsigned int u; } a, b; a.f = hi; b.f = lo;
    return __builtin_amdgcn_perm(a.u + 0x8000u, b.u + 0x8000u, 0x07060302u);
}
__device__ __forceinline__ float sigm(float x) {
    return __builtin_amdgcn_rcpf(1.f + __expf(-x));
}
__device__ __forceinline__ float tanh_fast(float x) {
    return 1.f - 2.f * __builtin_amdgcn_rcpf(__expf(2.f * x) + 1.f);
}
// 8 f32 -> 8 fp8 e4m3 packed in uint2
__device__ __forceinline__ uint2 pack8fp8(const float* f) {
    int lo = __builtin_amdgcn_cvt_pk_fp8_f32(f[0], f[1], 0, 0);
    lo = __builtin_amdgcn_cvt_pk_fp8_f32(f[2], f[3], lo, 1);
    int hi = __builtin_amdgcn_cvt_pk_fp8_f32(f[4], f[5], 0, 0);
    hi = __builtin_amdgcn_cvt_pk_fp8_f32(f[6], f[7], hi, 1);
    uint2 o; o.x = (unsigned int)lo; o.y = (unsigned int)hi; return o;
}
// 8 fp8 e4m3 (uint2) -> 8 f32
__device__ __forceinline__ void fp8x8_to_f32(uint2 v, float* f) {
    f32x2 a = __builtin_amdgcn_cvt_pk_f32_fp8((int)v.x, false);
    f32x2 b = __builtin_amdgcn_cvt_pk_f32_fp8((int)v.x, true);
    f32x2 c = __builtin_amdgcn_cvt_pk_f32_fp8((int)v.y, false);
    f32x2 d = __builtin_amdgcn_cvt_pk_f32_fp8((int)v.y, true);
    f[0] = a.x; f[1] = a.y; f[2] = b.x; f[3] = b.y;
    f[4] = c.x; f[5] = c.y; f[6] = d.x; f[7] = d.y;
}

// ---------------- prep: vocab tables, split-k over 4 blocks (atomicAdd) -----
__global__ __launch_bounds__(256) void prep_tables_sk(
    const float* __restrict__ emb,
    const float* __restrict__ Wz_w, const float* __restrict__ Wz_b,
    const float* __restrict__ Wr_w, const float* __restrict__ Ur_b,
    const float* __restrict__ Wh_w, const float* __restrict__ Wh_b,
    const float* __restrict__ out_w, const float* __restrict__ out_b,
    float* __restrict__ embR, float* __restrict__ embZ,
    float* __restrict__ embH, float* __restrict__ embO)
{
    __shared__ __align__(16) float e[4][64];
    int t = threadIdx.x;
    int b0 = blockIdx.x * 4;
    int k0 = blockIdx.y * 64;
    e[t >> 6][t & 63] = emb[(b0 + (t >> 6)) * HD + k0 + (t & 63)];
    __syncthreads();
    float aR[4] = {0,0,0,0}, aZ[4] = {0,0,0,0}, aH[4] = {0,0,0,0}, aO[4] = {0,0,0,0};
    for (int kk = 0; kk < 64; kk++) {
        int k = k0 + kk;
        float wr = Wr_w[k * HD + t];
        float wz = Wz_w[k * HD + t];
        float wh = Wh_w[k * HD + t];
        float wo = out_w[k * HD + t];
        #pragma unroll
        for (int r = 0; r < 4; r++) {
            float ev = e[r][kk];
            aR[r] += ev * wr; aZ[r] += ev * wz; aH[r] += ev * wh; aO[r] += ev * wo;
        }
    }
    if (blockIdx.y == 0) {
        float br = Ur_b[t], bz = Wz_b[t], bh = Wh_b[t], bo = out_b[t];
        #pragma unroll
        for (int r = 0; r < 4; r++) { aR[r] += br; aZ[r] += bz; aH[r] += bh; aO[r] += bo; }
    }
    #pragma unroll
    for (int r = 0; r < 4; r++) {
        atomicAdd(&embR[(b0 + r) * HD + t], aR[r]);
        atomicAdd(&embZ[(b0 + r) * HD + t], aZ[r]);
        atomicAdd(&embH[(b0 + r) * HD + t], aH[r]);
        atomicAdd(&embO[(b0 + r) * HD + t], aO[r]);
    }
}

// h1tab[v] = sigmoid(embZ[v]) * tanh(embH[v])   (depth-0 closed form)
__global__ __launch_bounds__(256) void h1fill(
    const float* __restrict__ embZ, const float* __restrict__ embH,
    ush* __restrict__ h1tab)
{
    int i = blockIdx.x * HD + threadIdx.x;
    h1tab[i] = f2bf_fast(sigm(embZ[i]) * tanh_fast(embH[i]));
}

// embU[v] = h1tab[v] @ Ur_w  (780x256 rows, split-k atomic)
__global__ __launch_bounds__(256) void h1u_sk(
    const ush* __restrict__ h1tab, const float* __restrict__ Ur_w,
    float* __restrict__ embU)
{
    __shared__ __align__(16) float e[4][64];
    int t = threadIdx.x;
    int b0 = blockIdx.x * 4;
    int k0 = blockIdx.y * 64;
    e[t >> 6][t & 63] = bf2f(h1tab[(b0 + (t >> 6)) * HD + k0 + (t & 63)]);
    __syncthreads();
    float aU[4] = {0,0,0,0};
    for (int kk = 0; kk < 64; kk++) {
        float w = Ur_w[(k0 + kk) * HD + t];
        #pragma unroll
        for (int r = 0; r < 4; r++) aU[r] += e[r][kk] * w;
    }
    #pragma unroll
    for (int r = 0; r < 4; r++) atomicAdd(&embU[(b0 + r) * HD + t], aU[r]);
}

// weights: fragment-packed (Wz_p, Wh_p, Ur_p, Wo_p).
// packed addr for (n,k): f = (n>>4)*8 + (k>>5); lane = ((k>>3)&3)*16 + (n&15);
// elem = (f*64 + lane)*8 + (k&7)  -> fragment load = contiguous 1KiB/wave.
__global__ __launch_bounds__(256) void prep_wt(
    const float* __restrict__ Ur_w, const float* __restrict__ Wz_w,
    const float* __restrict__ Wh_w, const float* __restrict__ out_w,
    ush* __restrict__ Wo_p,
    ush* __restrict__ Wz_p, ush* __restrict__ Wh_p, ush* __restrict__ Ur_p)
{
    int idx = blockIdx.x * 256 + threadIdx.x;   // n*256 + k
    int n = idx >> 8, k = idx & 255;
    int paddr = ((((n >> 4) * 8 + (k >> 5)) * 64 + ((k >> 3) & 3) * 16 + (n & 15)) << 3) + (k & 7);
    Wo_p[paddr] = f2bf_fast(out_w[(HD + k) * HD + n]);
    Wz_p[paddr] = f2bf_fast(Wz_w[(HD + k) * HD + n]);
    Wh_p[paddr] = f2bf_fast(Wh_w[(HD + k) * HD + n]);
    Ur_p[paddr] = f2bf_fast(Ur_w[k * HD + n]);
}

__global__ __launch_bounds__(256) void prep_vmess(
    const int* __restrict__ fnode, const int* __restrict__ fmess,
    int* __restrict__ v_mess)
{
    int m = blockIdx.x * 256 + threadIdx.x;
    v_mess[m] = fnode[fmess[m]];
}

// depth-0 fill: h[m] = h1tab[v] (bf16), hU8[m] = fp8(embU[v]); row 0 = 0
__global__ __launch_bounds__(256) void fill_h1(
    const ush* __restrict__ h1tab, const float* __restrict__ embU,
    const int* __restrict__ v_mess,
    ush* __restrict__ h, u8* __restrict__ hU8)
{
    int t = blockIdx.x * 256 + threadIdx.x;
    int m = t >> 5;
    int c = (t & 31) * 8;
    int v = v_mess[m];
    s16x8 o = *(const s16x8*)&h1tab[v * HD + c];
    float u[8];
    *(float4*)&u[0] = *(const float4*)&embU[v * HD + c];
    *(float4*)&u[4] = *(const float4*)&embU[v * HD + c + 4];
    uint2 up = pack8fp8(u);
    if (m == 0) { o = (s16x8){0,0,0,0,0,0,0,0}; up.x = up.y = 0; }
    *(s16x8*)&h[(size_t)m * HD + c] = o;
    *(uint2*)&hU8[(size_t)m * HD + c] = up;
}

// ---------------- fused step: gather + Z/P GEMM + GRU + U-GEMM --------------
// 32 messages/block, 256 threads (4 waves), LDS 33.8 KiB -> 4 blocks/CU.
template<int EMIT_HU>
__global__ __launch_bounds__(256, 4) void fused_step(
    const ush* __restrict__ h, const u8* __restrict__ hU8,
    const int* __restrict__ mg, const int* __restrict__ v_mess,
    const float* __restrict__ embR, const float* __restrict__ embZ,
    const float* __restrict__ embH,
    const ush* __restrict__ Wz_p, const ush* __restrict__ Wh_p,
    const ush* __restrict__ Ur_p,
    ush* __restrict__ h_next, u8* __restrict__ hU8_next)
{
    __shared__ __align__(16) ush sh[BMF * LDF];   // sum_h tile  (16.9 KiB)
    __shared__ __align__(16) ush sg[BMF * LDF];   // sum_gh tile -> h_next tile
    int tid = threadIdx.x;
    int wv = tid >> 6, lane = tid & 63;
    int quad = lane >> 4, l16 = lane & 15;
    int m0 = blockIdx.x * BMF;

    // ---- phase 1: gather + r-gate into LDS ----
    #pragma unroll 2
    for (int it = 0; it < 4; it++) {
        int g = it * 256 + tid;
        int ml = g >> 5;               // 0..31
        int c = (g & 31) * 8;          // 0..248
        int m = m0 + ml;
        int v = v_mess[m];
        float rb[8];
        *(float4*)&rb[0] = *(const float4*)&embR[v * HD + c];
        *(float4*)&rb[4] = *(const float4*)&embR[v * HD + c + 4];
        float ah[8] = {0,0,0,0,0,0,0,0};
        float ag[8] = {0,0,0,0,0,0,0,0};
        #pragma unroll
        for (int kn = 0; kn < MAXNEI; kn++) {
            int j = mg[m * MAXNEI + kn];
            s16x8 hv = *(const s16x8*)&h[(size_t)j * HD + c];
            uint2 uv8 = *(const uint2*)&hU8[(size_t)j * HD + c];
            float uf[8];
            fp8x8_to_f32(uv8, uf);
            #pragma unroll
            for (int e = 0; e < 8; e++) {
                float hf = bf2f((ush)hv[e]);
                ah[e] += hf;
                ag[e] += sigm(rb[e] + uf[e]) * hf;
            }
        }
        uint4 oh, og;
        oh.x = pack2bf(ah[1], ah[0]); oh.y = pack2bf(ah[3], ah[2]);
        oh.z = pack2bf(ah[5], ah[4]); oh.w = pack2bf(ah[7], ah[6]);
        og.x = pack2bf(ag[1], ag[0]); og.y = pack2bf(ag[3], ag[2]);
        og.z = pack2bf(ag[5], ag[4]); og.w = pack2bf(ag[7], ag[6]);
        *(uint4*)&sh[ml * LDF + c] = oh;
        *(uint4*)&sg[ml * LDF + c] = og;
    }
    __syncthreads();

    // ---- phase 2: Z = sum_h @ Wz2, P = sum_gh @ Wh2 (B frags from global) ----
    f32x4v az[2][4] = {}, ap[2][4] = {};
    #pragma unroll
    for (int ksi = 0; ksi < 8; ksi++) {
        int ks = ksi * 32;
        bfrag ahf[2], agf[2], bz[4], bh[4];
        #pragma unroll
        for (int i = 0; i < 2; i++) {
            ahf[i] = *(const bfrag*)&sh[(i * 16 + l16) * LDF + ks + quad * 8];
            agf[i] = *(const bfrag*)&sg[(i * 16 + l16) * LDF + ks + quad * 8];
        }
        #pragma unroll
        for (int j = 0; j < 4; j++) {
            int f = ((wv * 4 + j) * 8 + ksi) * 64 + lane;
            bz[j] = *(const bfrag*)&Wz_p[(size_t)f * 8];
            bh[j] = *(const bfrag*)&Wh_p[(size_t)f * 8];
        }
        #pragma unroll
        for (int i = 0; i < 2; i++)
            #pragma unroll
            for (int j = 0; j < 4; j++) {
                az[i][j] = __builtin_amdgcn_mfma_f32_16x16x32_bf16(ahf[i], bz[j], az[i][j], 0, 0, 0);
                ap[i][j] = __builtin_amdgcn_mfma_f32_16x16x32_bf16(agf[i], bh[j], ap[i][j], 0, 0, 0);
            }
    }

    // ---- GRU combine: az[i][j][r] <- h_next value (reuse regs) ----
    #pragma unroll
    for (int i = 0; i < 2; i++) {
        #pragma unroll
        for (int r = 0; r < 4; r++) {
            int rl = i * 16 + quad * 4 + r;
            int Rg = m0 + rl;
            int v = v_mess[Rg];
            #pragma unroll
            for (int j = 0; j < 4; j++) {
                int col = wv * 64 + j * 16 + l16;
                float z = sigm(az[i][j][r] + embZ[v * HD + col]);
                float pre = tanh_fast(ap[i][j][r] + embH[v * HD + col]);
                float shv = bf2f(sh[rl * LDF + col]);
                float hn = (1.f - z) * shv + z * pre;
                if (Rg == 0) hn = 0.f;
                az[i][j][r] = hn;
            }
        }
    }
    __syncthreads();   // all sh/sg reads done

    // ---- h_next tile into sg (LDS), then coalesced bf16 global write ----
    #pragma unroll
    for (int i = 0; i < 2; i++)
        #pragma unroll
        for (int j = 0; j < 4; j++) {
            int col = wv * 64 + j * 16 + l16;
            #pragma unroll
            for (int r = 0; r < 4; r++)
                sg[(i * 16 + quad * 4 + r) * LDF + col] = f2bf_fast(az[i][j][r]);
        }
    __syncthreads();
    #pragma unroll
    for (int it = 0; it < 4; it++) {
        int g = it * 256 + tid;
        int ml = g >> 5;
        int c = (g & 31) * 8;
        *(uint4*)&h_next[(size_t)(m0 + ml) * HD + c] = *(const uint4*)&sg[ml * LDF + c];
    }

    if (EMIT_HU) {
        // ---- U-GEMM: hU_next = h_next @ Ur  (A frags from sg, bf16) ----
        f32x4v au[2][4] = {};
        #pragma unroll
        for (int ksi = 0; ksi < 8; ksi++) {
            int ks = ksi * 32;
            bfrag af[2], bu[4];
            #pragma unroll
            for (int i = 0; i < 2; i++)
                af[i] = *(const bfrag*)&sg[(i * 16 + l16) * LDF + ks + quad * 8];
            #pragma unroll
            for (int j = 0; j < 4; j++) {
                int f = ((wv * 4 + j) * 8 + ksi) * 64 + lane;
                bu[j] = *(const bfrag*)&Ur_p[(size_t)f * 8];
            }
            #pragma unroll
            for (int i = 0; i < 2; i++)
                #pragma unroll
                for (int j = 0; j < 4; j++)
                    au[i][j] = __builtin_amdgcn_mfma_f32_16x16x32_bf16(af[i], bu[j], au[i][j], 0, 0, 0);
        }
        // write au (bf16) into sh, then coalesced fp8 pack + store
        #pragma unroll
        for (int i = 0; i < 2; i++)
            #pragma unroll
            for (int j = 0; j < 4; j++) {
                int col = wv * 64 + j * 16 + l16;
                #pragma unroll
                for (int r = 0; r < 4; r++)
                    sh[(i * 16 + quad * 4 + r) * LDF + col] = f2bf_fast(au[i][j][r]);
            }
        __syncthreads();
        #pragma unroll
        for (int it = 0; it < 4; it++) {
            int g = it * 256 + tid;
            int ml = g >> 5;
            int c = (g & 31) * 8;
            uint4 w = *(const uint4*)&sh[ml * LDF + c];
            float f[8] = { bfu_lo(w.x), bfu_hi(w.x), bfu_lo(w.y), bfu_hi(w.y),
                           bfu_lo(w.z), bfu_hi(w.z), bfu_lo(w.w), bfu_hi(w.w) };
            uint2 o = pack8fp8(f);
            *(uint2*)&hU8_next[(size_t)(m0 + ml) * HD + c] = o;
        }
    }
}

// ---------------- fused tail: node gather + out-projection GEMM -------------
// 32 nodes/block, 256 threads; gathers 5-neighbor h-sums into LDS, MFMA vs
// fragment-packed Wo_p, relu(acc + embO[fnode]) epilogue -> node_vec f32.
__global__ __launch_bounds__(256) void gather_out(
    const ush* __restrict__ h, const int* __restrict__ ng,
    const int* __restrict__ fnode, const float* __restrict__ embO,
    const ush* __restrict__ Wo_p, float* __restrict__ node_vec)
{
    __shared__ __align__(16) ush sh[BMF * LDF];
    int tid = threadIdx.x;
    int wv = tid >> 6, lane = tid & 63;
    int quad = lane >> 4, l16 = lane & 15;
    int n0 = blockIdx.x * BMF;

    #pragma unroll 2
    for (int it = 0; it < 4; it++) {
        int g = it * 256 + tid;
        int ml = g >> 5;
        int c = (g & 31) * 8;
        int n = n0 + ml;
        float a[8] = {0,0,0,0,0,0,0,0};
        #pragma unroll
        for (int kn = 0; kn < MAXNEI; kn++) {
            int j = ng[n * MAXNEI + kn];
            s16x8 hv = *(const s16x8*)&h[(size_t)j * HD + c];
            #pragma unroll
            for (int e = 0; e < 8; e++) a[e] += bf2f((ush)hv[e]);
        }
        uint4 o;
        o.x = pack2bf(a[1], a[0]); o.y = pack2bf(a[3], a[2]);
        o.z = pack2bf(a[5], a[4]); o.w = pack2bf(a[7], a[6]);
        *(uint4*)&sh[ml * LDF + c] = o;
    }
    __syncthreads();

    f32x4v acc[2][4] = {};
    #pragma unroll
    for (int ksi = 0; ksi < 8; ksi++) {
        int ks = ksi * 32;
        bfrag af[2], bo[4];
        #pragma unroll
        for (int i = 0; i < 2; i++)
            af[i] = *(const bfrag*)&sh[(i * 16 + l16) * LDF + ks + quad * 8];
        #pragma unroll
        for (int j = 0; j < 4; j++) {
            int f = ((wv * 4 + j) * 8 + ksi) * 64 + lane;
            bo[j] = *(const bfrag*)&Wo_p[(size_t)f * 8];
        }
        #pragma unroll
        for (int i = 0; i < 2; i++)
            #pragma unroll
            for (int j = 0; j < 4; j++)
                acc[i][j] = __builtin_amdgcn_mfma_f32_16x16x32_bf16(af[i], bo[j], acc[i][j], 0, 0, 0);
    }

    #pragma unroll
    for (int i = 0; i < 2; i++) {
        #pragma unroll
        for (int r = 0; r < 4; r++) {
            int Rn = n0 + i * 16 + quad * 4 + r;
            int v = fnode[Rn];
            #pragma unroll
            for (int j = 0; j < 4; j++) {
                int col = wv * 64 + j * 16 + l16;
                float o = acc[i][j][r] + embO[v * HD + col];
                node_vec[(size_t)Rn * HD + col] = fmaxf(o, 0.f);
            }
        }
    }
}

// ---------------- per-tree segment mean (scope_ids sorted) ------------------
__device__ __forceinline__ int lower_bound_dev(const int* a, int n, int key) {
    int lo = 0, hi = n;
    while (lo < hi) { int mid = (lo + hi) >> 1; if (a[mid] < key) lo = mid + 1; else hi = mid; }
    return lo;
}

__global__ __launch_bounds__(256) void segment_mean(
    const float* __restrict__ node_vec, const int* __restrict__ scope,
    float* __restrict__ out)
{
    int t = blockIdx.x;
    int c = threadIdx.x;
    int lo = lower_bound_dev(scope, NNODES, t);
    int hi = lower_bound_dev(scope, NNODES, t + 1);
    float acc = 0.f;
    for (int n = lo; n < hi; n++) acc += node_vec[(size_t)n * HD + c];
    int cnt = hi - lo;
    out[t * HD + c] = cnt > 0 ? acc / (float)cnt : 0.f;
}

// ---------------------------------------------------------------------------
extern "C" void kernel_launch(void* const* d_in, const int* in_sizes, int n_in,
                              void* d_out, int out_size, void* d_ws, size_t ws_size,
                              hipStream_t stream)
{
    const int*   fnode      = (const int*)d_in[0];
    const int*   fmess      = (const int*)d_in[1];
    const int*   node_graph = (const int*)d_in[2];
    const int*   mess_graph = (const int*)d_in[3];
    const int*   scope_ids  = (const int*)d_in[4];
    const float* emb        = (const float*)d_in[5];
    const float* Wz_w       = (const float*)d_in[6];
    const float* Wz_b       = (const float*)d_in[7];
    const float* Wr_w       = (const float*)d_in[8];
    const float* Ur_w       = (const float*)d_in[9];
    const float* Ur_b       = (const float*)d_in[10];
    const float* Wh_w       = (const float*)d_in[11];
    const float* Wh_b       = (const float*)d_in[12];
    const float* out_w      = (const float*)d_in[13];
    const float* out_b      = (const float*)d_in[14];

    // ---- workspace carve (~197 MiB) ----
    char* ws = (char*)d_ws;
    const size_t MHB = (size_t)NMESS * HD * 2;         // 64 MiB bf16 full-M
    const size_t MH8 = (size_t)NMESS * HD;             // 32 MiB fp8 full-M
    ush* P0 = (ush*)ws; ws += MHB;                     // h ping
    ush* P1 = (ush*)ws; ws += MHB;                     // h pong
    u8* U0 = (u8*)ws; ws += MH8;                       // hU8 ping
    u8* U1 = (u8*)ws; ws += MH8;                       // hU8 pong (contiguous w/ U0)
    float* embR = (float*)ws; ws += (size_t)NVOCAB * HD * 4;
    float* embZ = (float*)ws; ws += (size_t)NVOCAB * HD * 4;
    float* embH = (float*)ws; ws += (size_t)NVOCAB * HD * 4;
    float* embO = (float*)ws; ws += (size_t)NVOCAB * HD * 4;
    float* embU = (float*)ws; ws += (size_t)NVOCAB * HD * 4;
    ush* h1tab = (ush*)ws; ws += (size_t)NVOCAB * HD * 2;
    ush* Wo_p  = (ush*)ws; ws += (size_t)HD * HD * 2;
    ush* Wz_p  = (ush*)ws; ws += (size_t)HD * HD * 2;
    ush* Wh_p  = (ush*)ws; ws += (size_t)HD * HD * 2;
    ush* Ur_p  = (ush*)ws; ws += (size_t)HD * HD * 2;
    int* v_mess = (int*)ws; ws += (size_t)NMESS * 4;
    float* node_vec = (float*)U0;                      // U0+U1 = 64 MiB, free post-loop
    if ((size_t)(ws - (char*)d_ws) > ws_size) return;  // fail loud, not fault

    hipMemsetAsync(embR, 0, (size_t)5 * NVOCAB * HD * 4, stream);  // embR..embU
    prep_tables_sk<<<dim3(NVOCAB / 4, 4), 256, 0, stream>>>(
        emb, Wz_w, Wz_b, Wr_w, Ur_b, Wh_w, Wh_b, out_w, out_b,
        embR, embZ, embH, embO);
    h1fill<<<NVOCAB, 256, 0, stream>>>(embZ, embH, h1tab);
    h1u_sk<<<dim3(NVOCAB / 4, 4), 256, 0, stream>>>(h1tab, Ur_w, embU);
    prep_wt<<<HD * HD / 256, 256, 0, stream>>>(Ur_w, Wz_w, Wh_w, out_w,
                                               Wo_p, Wz_p, Wh_p, Ur_p);
    prep_vmess<<<NMESS / 256, 256, 0, stream>>>(fnode, fmess, v_mess);
    fill_h1<<<NMESS * 32 / 256, 256, 0, stream>>>(h1tab, embU, v_mess, P0, U0);

    ush* hc = P0; ush* hn = P1;
    u8* uc = U0; u8* un = U1;
    for (int d = 1; d < 5; d++) {
        fused_step<1><<<NMESS / BMF, 256, 0, stream>>>(hc, uc, mess_graph, v_mess,
                                                       embR, embZ, embH,
                                                       Wz_p, Wh_p, Ur_p, hn, un);
        { ush* t = hc; hc = hn; hn = t; }
        { u8* t = uc; uc = un; un = t; }
    }
    fused_step<0><<<NMESS / BMF, 256, 0, stream>>>(hc, uc, mess_graph, v_mess,
                                                   embR, embZ, embH,
                                                   Wz_p, Wh_p, Ur_p, hn, nullptr);
    hc = hn;  // final h (bf16); hU8 buffers now free (node_vec aliases U0+U1)

    gather_out<<<NNODES / BMF, 256, 0, stream>>>(hc, node_graph, fnode, embO,
                                                 Wo_p, node_vec);
    segment_mean<<<NTREES, 256, 0, stream>>>(node_vec, scope_ids, (float*)d_out);
}

// Round 9
// 1045.850 us; speedup vs baseline: 2.4359x; 1.0298x over previous
//
#include <hip/hip_runtime.h>

// JTNN encoder, MI355X.
//  - hU = h @ Ur_w once per row, gathered (5x FLOP cut vs h_nei@Ur)
//  - h bf16 (fp8-h FAILED accuracy R7); hU fp8 e4m3 (validated safe R6)
//  - h + hU interleaved in ONE 768 B/row buffer HM: each neighbor gather is
//    a single contiguous 768 B random fetch (was 512 B + 256 B from two
//    arrays) -> half the random row activations
//  - x-side projections folded into per-VOCAB tables (780 rows, L2-resident)
//  - depth-0 closed form: h1 = sigma(embZ[v]) * tanh(embH[v]); hU1 = (h1tab@Ur)[v]
//  - fused_step: gather + Z/P GEMM + GRU update + U-GEMM in ONE kernel
//  - gather_out: node-side gather + out-projection GEMM fused

#define HD 256
#define NNODES 65536
#define NMESS 131072
#define NVOCAB 780
#define NTREES 2048
#define MAXNEI 5
#define BMF 32
#define LDF 264     // padded LDS stride (shorts)
#define ROWB 768    // HM row bytes: 512 h-bf16 + 256 u-fp8

typedef short bfrag __attribute__((ext_vector_type(8)));   // 8 bf16 in 4 VGPRs
typedef short s16x8 __attribute__((ext_vector_type(8)));
typedef float f32x4v __attribute__((ext_vector_type(4)));
typedef float f32x2 __attribute__((ext_vector_type(2)));
typedef unsigned short ush;
typedef unsigned char u8;

__device__ __forceinline__ float bf2f(ush u) {
    union { unsigned int u; float f; } v; v.u = ((unsigned int)u) << 16; return v.f;
}
__device__ __forceinline__ float bfu_lo(unsigned int w) {
    union { unsigned int u; float f; } v; v.u = w << 16; return v.f;
}
__device__ __forceinline__ float bfu_hi(unsigned int w) {
    union { unsigned int u; float f; } v; v.u = w & 0xffff0000u; return v.f;
}
__device__ __forceinline__ ush f2bf_fast(float f) {
    union { float f; unsigned int u; } v; v.f = f;
    return (ush)((v.u + 0x8000u) >> 16);
}
// pack two f32 -> two bf16 (round-half-up) in one uint via v_perm
__device__ __forceinline__ unsigned int pack2bf(float hi, float lo) {
    union { float f; unsigned int u; } a, b; a.f = hi; b.f = lo;
    return __builtin_amdgcn_perm(a.u + 0x8000u, b.u + 0x8000u, 0x07060302u);
}
__device__ __forceinline__ float sigm(float x) {
    return __builtin_amdgcn_rcpf(1.f + __expf(-x));
}
__device__ __forceinline__ float tanh_fast(float x) {
    return 1.f - 2.f * __builtin_amdgcn_rcpf(__expf(2.f * x) + 1.f);
}
// 8 f32 -> 8 fp8 e4m3 packed in uint2
__device__ __forceinline__ uint2 pack8fp8(const float* f) {
    int lo = __builtin_amdgcn_cvt_pk_fp8_f32(f[0], f[1], 0, 0);
    lo = __builtin_amdgcn_cvt_pk_fp8_f32(f[2], f[3], lo, 1);
    int hi = __builtin_amdgcn_cvt_pk_fp8_f32(f[4], f[5], 0, 0);
    hi = __builtin_amdgcn_cvt_pk_fp8_f32(f[6], f[7], hi, 1);
    uint2 o; o.x = (unsigned int)lo; o.y = (unsigned int)hi; return o;
}
// 8 fp8 e4m3 (uint2) -> 8 f32
__device__ __forceinline__ void fp8x8_to_f32(uint2 v, float* f) {
    f32x2 a = __builtin_amdgcn_cvt_pk_f32_fp8((int)v.x, false);
    f32x2 b = __builtin_amdgcn_cvt_pk_f32_fp8((int)v.x, true);
    f32x2 c = __builtin_amdgcn_cvt_pk_f32_fp8((int)v.y, false);
    f32x2 d = __builtin_amdgcn_cvt_pk_f32_fp8((int)v.y, true);
    f[0] = a.x; f[1] = a.y; f[2] = b.x; f[3] = b.y;
    f[4] = c.x; f[5] = c.y; f[6] = d.x; f[7] = d.y;
}

// ---------------- prep: vocab tables, split-k over 4 blocks (atomicAdd) -----
__global__ __launch_bounds__(256) void prep_tables_sk(
    const float* __restrict__ emb,
    const float* __restrict__ Wz_w, const float* __restrict__ Wz_b,
    const float* __restrict__ Wr_w, const float* __restrict__ Ur_b,
    const float* __restrict__ Wh_w, const float* __restrict__ Wh_b,
    const float* __restrict__ out_w, const float* __restrict__ out_b,
    float* __restrict__ embR, float* __restrict__ embZ,
    float* __restrict__ embH, float* __restrict__ embO)
{
    __shared__ __align__(16) float e[4][64];
    int t = threadIdx.x;
    int b0 = blockIdx.x * 4;
    int k0 = blockIdx.y * 64;
    e[t >> 6][t & 63] = emb[(b0 + (t >> 6)) * HD + k0 + (t & 63)];
    __syncthreads();
    float aR[4] = {0,0,0,0}, aZ[4] = {0,0,0,0}, aH[4] = {0,0,0,0}, aO[4] = {0,0,0,0};
    for (int kk = 0; kk < 64; kk++) {
        int k = k0 + kk;
        float wr = Wr_w[k * HD + t];
        float wz = Wz_w[k * HD + t];
        float wh = Wh_w[k * HD + t];
        float wo = out_w[k * HD + t];
        #pragma unroll
        for (int r = 0; r < 4; r++) {
            float ev = e[r][kk];
            aR[r] += ev * wr; aZ[r] += ev * wz; aH[r] += ev * wh; aO[r] += ev * wo;
        }
    }
    if (blockIdx.y == 0) {
        float br = Ur_b[t], bz = Wz_b[t], bh = Wh_b[t], bo = out_b[t];
        #pragma unroll
        for (int r = 0; r < 4; r++) { aR[r] += br; aZ[r] += bz; aH[r] += bh; aO[r] += bo; }
    }
    #pragma unroll
    for (int r = 0; r < 4; r++) {
        atomicAdd(&embR[(b0 + r) * HD + t], aR[r]);
        atomicAdd(&embZ[(b0 + r) * HD + t], aZ[r]);
        atomicAdd(&embH[(b0 + r) * HD + t], aH[r]);
        atomicAdd(&embO[(b0 + r) * HD + t], aO[r]);
    }
}

// h1tab[v] = sigmoid(embZ[v]) * tanh(embH[v])   (depth-0 closed form)
__global__ __launch_bounds__(256) void h1fill(
    const float* __restrict__ embZ, const float* __restrict__ embH,
    ush* __restrict__ h1tab)
{
    int i = blockIdx.x * HD + threadIdx.x;
    h1tab[i] = f2bf_fast(sigm(embZ[i]) * tanh_fast(embH[i]));
}

// embU[v] = h1tab[v] @ Ur_w  (780x256 rows, split-k atomic)
__global__ __launch_bounds__(256) void h1u_sk(
    const ush* __restrict__ h1tab, const float* __restrict__ Ur_w,
    float* __restrict__ embU)
{
    __shared__ __align__(16) float e[4][64];
    int t = threadIdx.x;
    int b0 = blockIdx.x * 4;
    int k0 = blockIdx.y * 64;
    e[t >> 6][t & 63] = bf2f(h1tab[(b0 + (t >> 6)) * HD + k0 + (t & 63)]);
    __syncthreads();
    float aU[4] = {0,0,0,0};
    for (int kk = 0; kk < 64; kk++) {
        float w = Ur_w[(k0 + kk) * HD + t];
        #pragma unroll
        for (int r = 0; r < 4; r++) aU[r] += e[r][kk] * w;
    }
    #pragma unroll
    for (int r = 0; r < 4; r++) atomicAdd(&embU[(b0 + r) * HD + t], aU[r]);
}

// weights: fragment-packed (Wz_p, Wh_p, Ur_p, Wo_p).
// packed addr for (n,k): f = (n>>4)*8 + (k>>5); lane = ((k>>3)&3)*16 + (n&15);
// elem = (f*64 + lane)*8 + (k&7)  -> fragment load = contiguous 1KiB/wave.
__global__ __launch_bounds__(256) void prep_wt(
    const float* __restrict__ Ur_w, const float* __restrict__ Wz_w,
    const float* __restrict__ Wh_w, const float* __restrict__ out_w,
    ush* __restrict__ Wo_p,
    ush* __restrict__ Wz_p, ush* __restrict__ Wh_p, ush* __restrict__ Ur_p)
{
    int idx = blockIdx.x * 256 + threadIdx.x;   // n*256 + k
    int n = idx >> 8, k = idx & 255;
    int paddr = ((((n >> 4) * 8 + (k >> 5)) * 64 + ((k >> 3) & 3) * 16 + (n & 15)) << 3) + (k & 7);
    Wo_p[paddr] = f2bf_fast(out_w[(HD + k) * HD + n]);
    Wz_p[paddr] = f2bf_fast(Wz_w[(HD + k) * HD + n]);
    Wh_p[paddr] = f2bf_fast(Wh_w[(HD + k) * HD + n]);
    Ur_p[paddr] = f2bf_fast(Ur_w[k * HD + n]);
}

__global__ __launch_bounds__(256) void prep_vmess(
    const int* __restrict__ fnode, const int* __restrict__ fmess,
    int* __restrict__ v_mess)
{
    int m = blockIdx.x * 256 + threadIdx.x;
    v_mess[m] = fnode[fmess[m]];
}

// depth-0 fill: HM row m = [h1tab[v] bf16 | fp8(embU[v])]; row 0 = 0
__global__ __launch_bounds__(256) void fill_h1(
    const ush* __restrict__ h1tab, const float* __restrict__ embU,
    const int* __restrict__ v_mess, u8* __restrict__ HM)
{
    int t = blockIdx.x * 256 + threadIdx.x;
    int m = t >> 5;
    int c = (t & 31) * 8;          // elem offset 0..248
    int v = v_mess[m];
    s16x8 o = *(const s16x8*)&h1tab[v * HD + c];
    float u[8];
    *(float4*)&u[0] = *(const float4*)&embU[v * HD + c];
    *(float4*)&u[4] = *(const float4*)&embU[v * HD + c + 4];
    uint2 up = pack8fp8(u);
    if (m == 0) { o = (s16x8){0,0,0,0,0,0,0,0}; up.x = up.y = 0; }
    u8* row = HM + (size_t)m * ROWB;
    *(s16x8*)(row + 2 * c) = o;
    *(uint2*)(row + 512 + c) = up;
}

// ---------------- fused step: gather + Z/P GEMM + GRU + U-GEMM --------------
// 32 messages/block, 256 threads (4 waves), LDS 33.8 KiB -> 4 blocks/CU.
template<int EMIT_HU>
__global__ __launch_bounds__(256, 4) void fused_step(
    const u8* __restrict__ HM, const int* __restrict__ mg,
    const int* __restrict__ v_mess,
    const float* __restrict__ embR, const float* __restrict__ embZ,
    const float* __restrict__ embH,
    const ush* __restrict__ Wz_p, const ush* __restrict__ Wh_p,
    const ush* __restrict__ Ur_p,
    u8* __restrict__ HM_next)
{
    __shared__ __align__(16) ush sh[BMF * LDF];   // sum_h tile  (16.9 KiB)
    __shared__ __align__(16) ush sg[BMF * LDF];   // sum_gh tile -> h_next tile
    int tid = threadIdx.x;
    int wv = tid >> 6, lane = tid & 63;
    int quad = lane >> 4, l16 = lane & 15;
    int m0 = blockIdx.x * BMF;

    // ---- phase 1: gather + r-gate into LDS (one 768B row fetch/neighbor) ----
    #pragma unroll 2
    for (int it = 0; it < 4; it++) {
        int g = it * 256 + tid;
        int ml = g >> 5;               // 0..31
        int c = (g & 31) * 8;          // 0..248
        int m = m0 + ml;
        int v = v_mess[m];
        float rb[8];
        *(float4*)&rb[0] = *(const float4*)&embR[v * HD + c];
        *(float4*)&rb[4] = *(const float4*)&embR[v * HD + c + 4];
        float ah[8] = {0,0,0,0,0,0,0,0};
        float ag[8] = {0,0,0,0,0,0,0,0};
        #pragma unroll
        for (int kn = 0; kn < MAXNEI; kn++) {
            int j = mg[m * MAXNEI + kn];
            const u8* row = HM + (size_t)j * ROWB;
            s16x8 hv = *(const s16x8*)(row + 2 * c);
            uint2 uv8 = *(const uint2*)(row + 512 + c);
            float uf[8];
            fp8x8_to_f32(uv8, uf);
            #pragma unroll
            for (int e = 0; e < 8; e++) {
                float hf = bf2f((ush)hv[e]);
                ah[e] += hf;
                ag[e] += sigm(rb[e] + uf[e]) * hf;
            }
        }
        uint4 oh, og;
        oh.x = pack2bf(ah[1], ah[0]); oh.y = pack2bf(ah[3], ah[2]);
        oh.z = pack2bf(ah[5], ah[4]); oh.w = pack2bf(ah[7], ah[6]);
        og.x = pack2bf(ag[1], ag[0]); og.y = pack2bf(ag[3], ag[2]);
        og.z = pack2bf(ag[5], ag[4]); og.w = pack2bf(ag[7], ag[6]);
        *(uint4*)&sh[ml * LDF + c] = oh;
        *(uint4*)&sg[ml * LDF + c] = og;
    }
    __syncthreads();

    // ---- phase 2: Z = sum_h @ Wz2, P = sum_gh @ Wh2 (B frags from global) ----
    f32x4v az[2][4] = {}, ap[2][4] = {};
    #pragma unroll
    for (int ksi = 0; ksi < 8; ksi++) {
        int ks = ksi * 32;
        bfrag ahf[2], agf[2], bz[4], bh[4];
        #pragma unroll
        for (int i = 0; i < 2; i++) {
            ahf[i] = *(const bfrag*)&sh[(i * 16 + l16) * LDF + ks + quad * 8];
            agf[i] = *(const bfrag*)&sg[(i * 16 + l16) * LDF + ks + quad * 8];
        }
        #pragma unroll
        for (int j = 0; j < 4; j++) {
            int f = ((wv * 4 + j) * 8 + ksi) * 64 + lane;
            bz[j] = *(const bfrag*)&Wz_p[(size_t)f * 8];
            bh[j] = *(const bfrag*)&Wh_p[(size_t)f * 8];
        }
        #pragma unroll
        for (int i = 0; i < 2; i++)
            #pragma unroll
            for (int j = 0; j < 4; j++) {
                az[i][j] = __builtin_amdgcn_mfma_f32_16x16x32_bf16(ahf[i], bz[j], az[i][j], 0, 0, 0);
                ap[i][j] = __builtin_amdgcn_mfma_f32_16x16x32_bf16(agf[i], bh[j], ap[i][j], 0, 0, 0);
            }
    }

    // ---- GRU combine: az[i][j][r] <- h_next value (reuse regs) ----
    #pragma unroll
    for (int i = 0; i < 2; i++) {
        #pragma unroll
        for (int r = 0; r < 4; r++) {
            int rl = i * 16 + quad * 4 + r;
            int Rg = m0 + rl;
            int v = v_mess[Rg];
            #pragma unroll
            for (int j = 0; j < 4; j++) {
                int col = wv * 64 + j * 16 + l16;
                float z = sigm(az[i][j][r] + embZ[v * HD + col]);
                float pre = tanh_fast(ap[i][j][r] + embH[v * HD + col]);
                float shv = bf2f(sh[rl * LDF + col]);
                float hn = (1.f - z) * shv + z * pre;
                if (Rg == 0) hn = 0.f;
                az[i][j][r] = hn;
            }
        }
    }
    __syncthreads();   // all sh/sg reads done

    // ---- h_next tile into sg (LDS), then coalesced bf16 write to HM_next ----
    #pragma unroll
    for (int i = 0; i < 2; i++)
        #pragma unroll
        for (int j = 0; j < 4; j++) {
            int col = wv * 64 + j * 16 + l16;
            #pragma unroll
            for (int r = 0; r < 4; r++)
                sg[(i * 16 + quad * 4 + r) * LDF + col] = f2bf_fast(az[i][j][r]);
        }
    __syncthreads();
    #pragma unroll
    for (int it = 0; it < 4; it++) {
        int g = it * 256 + tid;
        int ml = g >> 5;
        int c = (g & 31) * 8;
        *(uint4*)(HM_next + (size_t)(m0 + ml) * ROWB + 2 * c) =
            *(const uint4*)&sg[ml * LDF + c];
    }

    if (EMIT_HU) {
        // ---- U-GEMM: hU_next = h_next @ Ur  (A frags from sg, bf16) ----
        f32x4v au[2][4] = {};
        #pragma unroll
        for (int ksi = 0; ksi < 8; ksi++) {
            int ks = ksi * 32;
            bfrag af[2], bu[4];
            #pragma unroll
            for (int i = 0; i < 2; i++)
                af[i] = *(const bfrag*)&sg[(i * 16 + l16) * LDF + ks + quad * 8];
            #pragma unroll
            for (int j = 0; j < 4; j++) {
                int f = ((wv * 4 + j) * 8 + ksi) * 64 + lane;
                bu[j] = *(const bfrag*)&Ur_p[(size_t)f * 8];
            }
            #pragma unroll
            for (int i = 0; i < 2; i++)
                #pragma unroll
                for (int j = 0; j < 4; j++)
                    au[i][j] = __builtin_amdgcn_mfma_f32_16x16x32_bf16(af[i], bu[j], au[i][j], 0, 0, 0);
        }
        // write au (bf16) into sh, then coalesced fp8 pack + store
        #pragma unroll
        for (int i = 0; i < 2; i++)
            #pragma unroll
            for (int j = 0; j < 4; j++) {
                int col = wv * 64 + j * 16 + l16;
                #pragma unroll
                for (int r = 0; r < 4; r++)
                    sh[(i * 16 + quad * 4 + r) * LDF + col] = f2bf_fast(au[i][j][r]);
            }
        __syncthreads();
        #pragma unroll
        for (int it = 0; it < 4; it++) {
            int g = it * 256 + tid;
            int ml = g >> 5;
            int c = (g & 31) * 8;
            uint4 w = *(const uint4*)&sh[ml * LDF + c];
            float f[8] = { bfu_lo(w.x), bfu_hi(w.x), bfu_lo(w.y), bfu_hi(w.y),
                           bfu_lo(w.z), bfu_hi(w.z), bfu_lo(w.w), bfu_hi(w.w) };
            uint2 o = pack8fp8(f);
            *(uint2*)(HM_next + (size_t)(m0 + ml) * ROWB + 512 + c) = o;
        }
    }
}

// ---------------- fused tail: node gather + out-projection GEMM -------------
// 32 nodes/block; gathers 5-neighbor h-sums (h part of HM rows) into LDS,
// MFMA vs fragment-packed Wo_p, relu(acc + embO[fnode]) -> node_vec f32.
__global__ __launch_bounds__(256) void gather_out(
    const u8* __restrict__ HM, const int* __restrict__ ng,
    const int* __restrict__ fnode, const float* __restrict__ embO,
    const ush* __restrict__ Wo_p, float* __restrict__ node_vec)
{
    __shared__ __align__(16) ush sh[BMF * LDF];
    int tid = threadIdx.x;
    int wv = tid >> 6, lane = tid & 63;
    int quad = lane >> 4, l16 = lane & 15;
    int n0 = blockIdx.x * BMF;

    #pragma unroll 2
    for (int it = 0; it < 4; it++) {
        int g = it * 256 + tid;
        int ml = g >> 5;
        int c = (g & 31) * 8;
        int n = n0 + ml;
        float a[8] = {0,0,0,0,0,0,0,0};
        #pragma unroll
        for (int kn = 0; kn < MAXNEI; kn++) {
            int j = ng[n * MAXNEI + kn];
            s16x8 hv = *(const s16x8*)(HM + (size_t)j * ROWB + 2 * c);
            #pragma unroll
            for (int e = 0; e < 8; e++) a[e] += bf2f((ush)hv[e]);
        }
        uint4 o;
        o.x = pack2bf(a[1], a[0]); o.y = pack2bf(a[3], a[2]);
        o.z = pack2bf(a[5], a[4]); o.w = pack2bf(a[7], a[6]);
        *(uint4*)&sh[ml * LDF + c] = o;
    }
    __syncthreads();

    f32x4v acc[2][4] = {};
    #pragma unroll
    for (int ksi = 0; ksi < 8; ksi++) {
        int ks = ksi * 32;
        bfrag af[2], bo[4];
        #pragma unroll
        for (int i = 0; i < 2; i++)
            af[i] = *(const bfrag*)&sh[(i * 16 + l16) * LDF + ks + quad * 8];
        #pragma unroll
        for (int j = 0; j < 4; j++) {
            int f = ((wv * 4 + j) * 8 + ksi) * 64 + lane;
            bo[j] = *(const bfrag*)&Wo_p[(size_t)f * 8];
        }
        #pragma unroll
        for (int i = 0; i < 2; i++)
            #pragma unroll
            for (int j = 0; j < 4; j++)
                acc[i][j] = __builtin_amdgcn_mfma_f32_16x16x32_bf16(af[i], bo[j], acc[i][j], 0, 0, 0);
    }

    #pragma unroll
    for (int i = 0; i < 2; i++) {
        #pragma unroll
        for (int r = 0; r < 4; r++) {
            int Rn = n0 + i * 16 + quad * 4 + r;
            int v = fnode[Rn];
            #pragma unroll
            for (int j = 0; j < 4; j++) {
                int col = wv * 64 + j * 16 + l16;
                float o = acc[i][j][r] + embO[v * HD + col];
                node_vec[(size_t)Rn * HD + col] = fmaxf(o, 0.f);
            }
        }
    }
}

// ---------------- per-tree segment mean (scope_ids sorted) ------------------
__device__ __forceinline__ int lower_bound_dev(const int* a, int n, int key) {
    int lo = 0, hi = n;
    while (lo < hi) { int mid = (lo + hi) >> 1; if (a[mid] < key) lo = mid + 1; else hi = mid; }
    return lo;
}

__global__ __launch_bounds__(256) void segment_mean(
    const float* __restrict__ node_vec, const int* __restrict__ scope,
    float* __restrict__ out)
{
    int t = blockIdx.x;
    int c = threadIdx.x;
    int lo = lower_bound_dev(scope, NNODES, t);
    int hi = lower_bound_dev(scope, NNODES, t + 1);
    float acc = 0.f;
    for (int n = lo; n < hi; n++) acc += node_vec[(size_t)n * HD + c];
    int cnt = hi - lo;
    out[t * HD + c] = cnt > 0 ? acc / (float)cnt : 0.f;
}

// ---------------------------------------------------------------------------
extern "C" void kernel_launch(void* const* d_in, const int* in_sizes, int n_in,
                              void* d_out, int out_size, void* d_ws, size_t ws_size,
                              hipStream_t stream)
{
    const int*   fnode      = (const int*)d_in[0];
    const int*   fmess      = (const int*)d_in[1];
    const int*   node_graph = (const int*)d_in[2];
    const int*   mess_graph = (const int*)d_in[3];
    const int*   scope_ids  = (const int*)d_in[4];
    const float* emb        = (const float*)d_in[5];
    const float* Wz_w       = (const float*)d_in[6];
    const float* Wz_b       = (const float*)d_in[7];
    const float* Wr_w       = (const float*)d_in[8];
    const float* Ur_w       = (const float*)d_in[9];
    const float* Ur_b       = (const float*)d_in[10];
    const float* Wh_w       = (const float*)d_in[11];
    const float* Wh_b       = (const float*)d_in[12];
    const float* out_w      = (const float*)d_in[13];
    const float* out_b      = (const float*)d_in[14];

    // ---- workspace carve (~198 MiB) ----
    char* ws = (char*)d_ws;
    const size_t HMB = (size_t)NMESS * ROWB;           // 100.7 MB combined row buf
    u8* HM0 = (u8*)ws; ws += HMB;                      // ping
    u8* HM1 = (u8*)ws; ws += HMB;                      // pong
    float* embR = (float*)ws; ws += (size_t)NVOCAB * HD * 4;
    float* embZ = (float*)ws; ws += (size_t)NVOCAB * HD * 4;
    float* embH = (float*)ws; ws += (size_t)NVOCAB * HD * 4;
    float* embO = (float*)ws; ws += (size_t)NVOCAB * HD * 4;
    float* embU = (float*)ws; ws += (size_t)NVOCAB * HD * 4;
    ush* h1tab = (ush*)ws; ws += (size_t)NVOCAB * HD * 2;
    ush* Wo_p  = (ush*)ws; ws += (size_t)HD * HD * 2;
    ush* Wz_p  = (ush*)ws; ws += (size_t)HD * HD * 2;
    ush* Wh_p  = (ush*)ws; ws += (size_t)HD * HD * 2;
    ush* Ur_p  = (ush*)ws; ws += (size_t)HD * HD * 2;
    int* v_mess = (int*)ws; ws += (size_t)NMESS * 4;
    if ((size_t)(ws - (char*)d_ws) > ws_size) return;  // fail loud, not fault

    hipMemsetAsync(embR, 0, (size_t)5 * NVOCAB * HD * 4, stream);  // embR..embU
    prep_tables_sk<<<dim3(NVOCAB / 4, 4), 256, 0, stream>>>(
        emb, Wz_w, Wz_b, Wr_w, Ur_b, Wh_w, Wh_b, out_w, out_b,
        embR, embZ, embH, embO);
    h1fill<<<NVOCAB, 256, 0, stream>>>(embZ, embH, h1tab);
    h1u_sk<<<dim3(NVOCAB / 4, 4), 256, 0, stream>>>(h1tab, Ur_w, embU);
    prep_wt<<<HD * HD / 256, 256, 0, stream>>>(Ur_w, Wz_w, Wh_w, out_w,
                                               Wo_p, Wz_p, Wh_p, Ur_p);
    prep_vmess<<<NMESS / 256, 256, 0, stream>>>(fnode, fmess, v_mess);
    fill_h1<<<NMESS * 32 / 256, 256, 0, stream>>>(h1tab, embU, v_mess, HM0);

    u8* hc = HM0; u8* hn = HM1;
    for (int d = 1; d < 5; d++) {
        fused_step<1><<<NMESS / BMF, 256, 0, stream>>>(hc, mess_graph, v_mess,
                                                       embR, embZ, embH,
                                                       Wz_p, Wh_p, Ur_p, hn);
        u8* t = hc; hc = hn; hn = t;
    }
    fused_step<0><<<NMESS / BMF, 256, 0, stream>>>(hc, mess_graph, v_mess,
                                                   embR, embZ, embH,
                                                   Wz_p, Wh_p, Ur_p, hn);
    hc = hn;  // final HM (h part valid); the other buffer is free

    float* node_vec = (float*)(hc == HM0 ? HM1 : HM0);  // 67 MB < 100.7 MB ✓
    gather_out<<<NNODES / BMF, 256, 0, stream>>>(hc, node_graph, fnode, embO,
                                                 Wo_p, node_vec);
    segment_mean<<<NTREES, 256, 0, stream>>>(node_vec, scope_ids, (float*)d_out);
}